// Round 1
// baseline (790.378 us; speedup 1.0000x reference)
//
#include <hip/hip_runtime.h>

#define B_ 4
#define N_ 4096
#define DIM_ 512
#define H_ 8
#define DH_ 64
#define F_ 256
#define CS_ 128
#define C_ 32
#define M_ (B_*N_)        // 16384 token rows
#define QKVC_ (3*DIM_)    // 1536
#define NCHUNK_ (B_*H_*C_) // 1024

// ws layout (bytes):
//   qkv   fp32 [16384][1536]                 100,663,296
//   kp    bf16 [1024 chunks][128 s][256 f]    67,108,864  (ctx fp32 [1024][256][64] aliases this)
//   qp    bf16 same layout                    67,108,864
//   ksum  fp32 [1024][256]                     1,048,576
// total ~236 MB

__device__ __forceinline__ unsigned short f2bf(float x){
  unsigned int u = __float_as_uint(x);
  u += 0x7fffu + ((u >> 16) & 1u);          // RNE
  return (unsigned short)(u >> 16);
}
__device__ __forceinline__ float bf2f(unsigned short s){
  return __uint_as_float(((unsigned int)s) << 16);
}

// C[m][n] = sum_k A[m][k]*Bm[n][k] (+bias[n]). 128x128 tile, BK=8, 256 thr, 8x8/thread.
__global__ __launch_bounds__(256)
void sgemm_nt(const float* __restrict__ A, const float* __restrict__ Bm,
              float* __restrict__ Cm, const float* __restrict__ bias,
              int K, int lda, int ldb, int ldc)
{
  __shared__ float As[8][128];
  __shared__ float Bs[8][128];
  const int tid = threadIdx.x;
  const int bm = blockIdx.y * 128;
  const int bn = blockIdx.x * 128;
  const int tx = tid & 15, ty = tid >> 4;
  const int lr = tid >> 1;             // 0..127
  const int lk = (tid & 1) * 4;        // 0 or 4
  const float* Ap = A + (size_t)(bm + lr) * lda + lk;
  const float* Bp = Bm + (size_t)(bn + lr) * ldb + lk;
  float acc[8][8];
#pragma unroll
  for (int i = 0; i < 8; ++i)
#pragma unroll
    for (int j = 0; j < 8; ++j) acc[i][j] = 0.f;

  for (int k0 = 0; k0 < K; k0 += 8) {
    float4 av = *(const float4*)(Ap + k0);
    float4 bv = *(const float4*)(Bp + k0);
    __syncthreads();
    As[lk+0][lr] = av.x; As[lk+1][lr] = av.y; As[lk+2][lr] = av.z; As[lk+3][lr] = av.w;
    Bs[lk+0][lr] = bv.x; Bs[lk+1][lr] = bv.y; Bs[lk+2][lr] = bv.z; Bs[lk+3][lr] = bv.w;
    __syncthreads();
#pragma unroll
    for (int kk = 0; kk < 8; ++kk) {
      float a[8], b[8];
      *(float4*)&a[0] = *(const float4*)&As[kk][ty*4];
      *(float4*)&a[4] = *(const float4*)&As[kk][64 + ty*4];
      *(float4*)&b[0] = *(const float4*)&Bs[kk][tx*4];
      *(float4*)&b[4] = *(const float4*)&Bs[kk][64 + tx*4];
#pragma unroll
      for (int i = 0; i < 8; ++i)
#pragma unroll
        for (int j = 0; j < 8; ++j)
          acc[i][j] = fmaf(a[i], b[j], acc[i][j]);
    }
  }
#pragma unroll
  for (int i = 0; i < 8; ++i) {
    int r = bm + ((i < 4) ? (ty*4 + i) : (64 + ty*4 + i - 4));
#pragma unroll
    for (int jh = 0; jh < 2; ++jh) {
      int cb = bn + jh*64 + tx*4;
      float o0 = acc[i][jh*4+0], o1 = acc[i][jh*4+1], o2 = acc[i][jh*4+2], o3 = acc[i][jh*4+3];
      if (bias) { o0 += bias[cb]; o1 += bias[cb+1]; o2 += bias[cb+2]; o3 += bias[cb+3]; }
      float4 o; o.x = o0; o.y = o1; o.z = o2; o.w = o3;
      *(float4*)(Cm + (size_t)r * ldc + cb) = o;
    }
  }
}

// Per 64-row half-chunk: tp = (t*scale) @ proj^T  [64 x 256], exact fp32 rowmax,
// exp, store bf16 to qp/kp in [chunk][s][f] layout.
__global__ __launch_bounds__(256)
void feat_kernel(const float* __restrict__ qkv, const float* __restrict__ proj,
                 unsigned short* __restrict__ qp, unsigned short* __restrict__ kp)
{
  __shared__ float As[32][68];     // [k][row], padded (16B-aligned rows)
  __shared__ float Bs[32][260];    // [k][f],  padded (16B-aligned rows)
  __shared__ float pmax[64][33];
  __shared__ float rowmax[64];
  const int tid = threadIdx.x;
  const int half = blockIdx.x;       // 0,1
  const int chunk = blockIdx.y;      // 0..1023
  const int p = blockIdx.z;          // 0=q, 1=k
  const int b = chunk >> 8, h = (chunk >> 5) & 7, c = chunk & 31;
  const int mbase = b * N_ + c * CS_ + half * 64;
  const int colbase = p * DIM_ + h * DH_;
  const float scale = (p == 0) ? 0.125f : 1.0f;
  const int tx = tid & 31, ty = tid >> 5;   // tx: f-dir (32), ty: row-dir (8)

  float acc[8][8];
#pragma unroll
  for (int i = 0; i < 8; ++i)
#pragma unroll
    for (int j = 0; j < 8; ++j) acc[i][j] = 0.f;

  for (int ks = 0; ks < 64; ks += 32) {
    __syncthreads();
    // stage t rows: 64 rows x 32 k -> 512 float4, 2/thread
#pragma unroll
    for (int j = 0; j < 2; ++j) {
      int idx = tid + j * 256;
      int r = idx >> 3, dq = idx & 7;
      float4 v = *(const float4*)(qkv + (size_t)(mbase + r) * QKVC_ + colbase + ks + dq*4);
      As[dq*4+0][r] = v.x * scale; As[dq*4+1][r] = v.y * scale;
      As[dq*4+2][r] = v.z * scale; As[dq*4+3][r] = v.w * scale;
    }
    // stage proj: 256 f x 32 k -> 2048 float4, 8/thread
#pragma unroll
    for (int j = 0; j < 8; ++j) {
      int idx = tid + j * 256;
      int f = idx >> 3, dq = idx & 7;
      float4 v = *(const float4*)(proj + (size_t)f * DH_ + ks + dq*4);
      Bs[dq*4+0][f] = v.x; Bs[dq*4+1][f] = v.y; Bs[dq*4+2][f] = v.z; Bs[dq*4+3][f] = v.w;
    }
    __syncthreads();
#pragma unroll
    for (int kk = 0; kk < 32; ++kk) {
      float a[8], bb[8];
      *(float4*)&a[0]  = *(const float4*)&As[kk][ty*4];
      *(float4*)&a[4]  = *(const float4*)&As[kk][32 + ty*4];
      *(float4*)&bb[0] = *(const float4*)&Bs[kk][tx*4];
      *(float4*)&bb[4] = *(const float4*)&Bs[kk][128 + tx*4];
#pragma unroll
      for (int i = 0; i < 8; ++i)
#pragma unroll
        for (int j = 0; j < 8; ++j)
          acc[i][j] = fmaf(a[i], bb[j], acc[i][j]);
    }
  }
  // exact rowmax over f (256)
#pragma unroll
  for (int i = 0; i < 8; ++i) {
    float m = acc[i][0];
#pragma unroll
    for (int j = 1; j < 8; ++j) m = fmaxf(m, acc[i][j]);
    int row = (i < 4) ? (ty*4 + i) : (32 + ty*4 + i - 4);
    pmax[row][tx] = m;
  }
  __syncthreads();
  if (tid < 64) {
    float m = pmax[tid][0];
    for (int i = 1; i < 32; ++i) m = fmaxf(m, pmax[tid][i]);
    rowmax[tid] = m;
  }
  __syncthreads();
  unsigned short* dst = ((p == 0) ? qp : kp)
                      + (size_t)chunk * (CS_ * F_) + (size_t)(half * 64) * F_;
#pragma unroll
  for (int i = 0; i < 8; ++i) {
    int row = (i < 4) ? (ty*4 + i) : (32 + ty*4 + i - 4);
    float rm = rowmax[row];
    unsigned int* w = (unsigned int*)(dst + (size_t)row * F_);
#pragma unroll
    for (int jh = 0; jh < 2; ++jh) {
      int f0 = jh*128 + tx*4;
      float v0 = __expf(acc[i][jh*4+0] - rm);
      float v1 = __expf(acc[i][jh*4+1] - rm);
      float v2 = __expf(acc[i][jh*4+2] - rm);
      float v3 = __expf(acc[i][jh*4+3] - rm);
      w[(f0 >> 1) + 0] = (unsigned int)f2bf(v0) | ((unsigned int)f2bf(v1) << 16);
      w[(f0 >> 1) + 1] = (unsigned int)f2bf(v2) | ((unsigned int)f2bf(v3) << 16);
    }
  }
}

// Per chunk: context[f][d] = sum_s kp[s][f]*v[s][d]; ksum[f] = sum_s kp[s][f].
// ctx (fp32) is written over this chunk's own kp region (same 64 KiB) after a barrier.
__global__ __launch_bounds__(256)
void ctx_kernel(const float* __restrict__ qkv, const unsigned short* kp,
                float* ctx, float* __restrict__ ksum)
{
  __shared__ float vs[128][64];
  const int tid = threadIdx.x;
  const int chunk = blockIdx.x;
  const int b = chunk >> 8, h = (chunk >> 5) & 7, c = chunk & 31;
  const int mbase = b * N_ + c * CS_;
  const int vcol = 2 * DIM_ + h * DH_;
#pragma unroll
  for (int j = 0; j < 8; ++j) {
    int idx = tid + j * 256;          // float4 index, 0..2047
    int r = idx >> 4, dq = idx & 15;
    *(float4*)&vs[r][dq*4] =
        *(const float4*)(qkv + (size_t)(mbase + r) * QKVC_ + vcol + dq*4);
  }
  __syncthreads();
  const unsigned short* kpc = kp + (size_t)chunk * (CS_ * F_) + tid;  // f = tid
  float cacc[64];
#pragma unroll
  for (int d = 0; d < 64; ++d) cacc[d] = 0.f;
  float ks = 0.f;
#pragma unroll 4
  for (int s = 0; s < CS_; ++s) {
    float kv = bf2f(kpc[s * F_]);
    ks += kv;
#pragma unroll
    for (int dq = 0; dq < 16; ++dq) {
      float4 v4 = *(const float4*)&vs[s][dq*4];
      cacc[dq*4+0] = fmaf(kv, v4.x, cacc[dq*4+0]);
      cacc[dq*4+1] = fmaf(kv, v4.y, cacc[dq*4+1]);
      cacc[dq*4+2] = fmaf(kv, v4.z, cacc[dq*4+2]);
      cacc[dq*4+3] = fmaf(kv, v4.w, cacc[dq*4+3]);
    }
  }
  __syncthreads();   // all kp reads in this block done before aliased ctx write
  ksum[(size_t)chunk * F_ + tid] = ks;
  float* cd = ctx + (size_t)chunk * (F_ * DH_) + (size_t)tid * DH_;
#pragma unroll
  for (int dq = 0; dq < 16; ++dq) {
    float4 o; o.x = cacc[dq*4+0]; o.y = cacc[dq*4+1]; o.z = cacc[dq*4+2]; o.w = cacc[dq*4+3];
    *(float4*)(cd + dq*4) = o;
  }
}

// Per chunk: D = qp·ksum, out = (qp @ ctx) / (D+1e-4), written over q region of qkv.
__global__ __launch_bounds__(256)
void out_kernel(const float* __restrict__ ctx, const unsigned short* __restrict__ qp,
                const float* __restrict__ ksum, float* qkv_attn)
{
  __shared__ float cs[F_ * DH_];          // [f*64+d], 64 KiB
  __shared__ unsigned int qsu[16][128];   // 16 s-rows, f packed in pairs
  __shared__ float ksL[F_];
  __shared__ float dred[16][17];
  __shared__ float dinv[16];
  const int tid = threadIdx.x;
  const int chunk = blockIdx.x;
  const int b = chunk >> 8, h = (chunk >> 5) & 7, c = chunk & 31;
#pragma unroll
  for (int j = 0; j < 16; ++j) {
    int idx = tid + j * 256;              // float4 index 0..4095
    *(float4*)&cs[idx*4] = *(const float4*)(ctx + (size_t)chunk * (F_ * DH_) + idx*4);
  }
  ksL[tid] = ksum[(size_t)chunk * F_ + tid];
  const int sQ = tid >> 4;   // 0..15
  const int lq = tid & 15;   // 0..15
  for (int sl = 0; sl < 8; ++sl) {
    __syncthreads();
    const unsigned int* qsrc =
        (const unsigned int*)(qp + (size_t)chunk * (CS_ * F_) + (size_t)sl * 16 * F_);
#pragma unroll
    for (int j = 0; j < 8; ++j) {
      int idx = tid + j * 256;            // 0..2047
      qsu[idx >> 7][idx & 127] = qsrc[idx];
    }
    __syncthreads();
    float dp = 0.f;
#pragma unroll
    for (int j = 0; j < 8; ++j) {
      unsigned int u = qsu[sQ][lq*8 + j];
      dp = fmaf(bf2f((unsigned short)(u & 0xffffu)), ksL[lq*16 + 2*j],     dp);
      dp = fmaf(bf2f((unsigned short)(u >> 16)),     ksL[lq*16 + 2*j + 1], dp);
    }
    dred[sQ][lq] = dp;
    __syncthreads();
    if (tid < 16) {
      float D = 0.f;
      for (int i = 0; i < 16; ++i) D += dred[tid][i];
      dinv[tid] = 1.f / (D + 1e-4f);
    }
    __syncthreads();
    float ox = 0.f, oy = 0.f, oz = 0.f, ow = 0.f;
    const float4* c4 = (const float4*)cs;
#pragma unroll 4
    for (int fu = 0; fu < 128; ++fu) {
      unsigned int u = qsu[sQ][fu];
      float qa = bf2f((unsigned short)(u & 0xffffu));
      float qb = bf2f((unsigned short)(u >> 16));
      float4 ca = c4[(2*fu    ) * 16 + lq];
      float4 cb = c4[(2*fu + 1) * 16 + lq];
      ox = fmaf(qa, ca.x, ox); oy = fmaf(qa, ca.y, oy);
      oz = fmaf(qa, ca.z, oz); ow = fmaf(qa, ca.w, ow);
      ox = fmaf(qb, cb.x, ox); oy = fmaf(qb, cb.y, oy);
      oz = fmaf(qb, cb.z, oz); ow = fmaf(qb, cb.w, ow);
    }
    float di = dinv[sQ];
    float4 o; o.x = ox*di; o.y = oy*di; o.z = oz*di; o.w = ow*di;
    int m = b * N_ + c * CS_ + sl * 16 + sQ;
    *(float4*)(qkv_attn + (size_t)m * QKVC_ + h * DH_ + lq*4) = o;
  }
}

extern "C" void kernel_launch(void* const* d_in, const int* in_sizes, int n_in,
                              void* d_out, int out_size, void* d_ws, size_t ws_size,
                              hipStream_t stream)
{
  const float* x     = (const float*)d_in[0];
  const float* w_qkv = (const float*)d_in[1];
  const float* w_out = (const float*)d_in[2];
  const float* b_out = (const float*)d_in[3];
  const float* proj  = (const float*)d_in[4];
  float* out = (float*)d_out;

  float* qkv = (float*)d_ws;
  const size_t qkv_elems = (size_t)M_ * QKVC_;          // 25,165,824 floats
  unsigned short* kp = (unsigned short*)(qkv + qkv_elems);
  const size_t pf_elems = (size_t)NCHUNK_ * CS_ * F_;   // 33,554,432 bf16
  unsigned short* qp = kp + pf_elems;
  float* ksum = (float*)(qp + pf_elems);
  float* ctx = (float*)kp;   // deliberate alias: ctx chunk (64 KiB fp32) reuses kp chunk (64 KiB bf16)

  // 1) qkv = x @ w_qkv^T
  sgemm_nt<<<dim3(QKVC_/128, M_/128), 256, 0, stream>>>(x, w_qkv, qkv, nullptr,
                                                        DIM_, DIM_, DIM_, QKVC_);
  // 2) q' / k' features (bf16)
  feat_kernel<<<dim3(2, NCHUNK_, 2), 256, 0, stream>>>(qkv, proj, qp, kp);
  // 3) per-chunk context + ksum (ctx overwrites kp region)
  ctx_kernel<<<dim3(NCHUNK_), 256, 0, stream>>>(qkv, kp, ctx, ksum);
  // 4) per-chunk out, written over q region of qkv
  out_kernel<<<dim3(NCHUNK_), 256, 0, stream>>>(ctx, qp, ksum, qkv);
  // 5) out = attn @ w_out^T + b_out
  sgemm_nt<<<dim3(DIM_/128, M_/128), 256, 0, stream>>>(qkv, w_out, out, b_out,
                                                       DIM_, QKVC_, DIM_, DIM_);
}

// Round 2
// 551.983 us; speedup vs baseline: 1.4319x; 1.4319x over previous
//
#include <hip/hip_runtime.h>

#define B_ 4
#define N_ 4096
#define DIM_ 512
#define H_ 8
#define DH_ 64
#define F_ 256
#define CS_ 128
#define C_ 32
#define M_ (B_*N_)        // 16384 token rows
#define QKVC_ (3*DIM_)    // 1536
#define NCHUNK_ (B_*H_*C_) // 1024

typedef __attribute__((ext_vector_type(8))) short bf16x8;
typedef __attribute__((ext_vector_type(4))) float f32x4;

__device__ __forceinline__ unsigned short f2bf(float x){
  unsigned int u = __float_as_uint(x);
  u += 0x7fffu + ((u >> 16) & 1u);          // RNE
  return (unsigned short)(u >> 16);
}
__device__ __forceinline__ float bf2f(unsigned short s){
  return __uint_as_float(((unsigned int)s) << 16);
}

__device__ __forceinline__ void gl2lds16(const unsigned short* g, unsigned short* l) {
  __builtin_amdgcn_global_load_lds((const __attribute__((address_space(1))) unsigned int*)g,
                                   (__attribute__((address_space(3))) unsigned int*)l,
                                   16, 0, 0);
}

// Split fp32 -> bf16 hi + bf16 lo (hi = rnd(v), lo = rnd(v - hi)); float4-vectorized.
__global__ __launch_bounds__(256)
void split_kernel(const float* __restrict__ src, unsigned short* __restrict__ hi,
                  unsigned short* __restrict__ lo, int n4)
{
  int idx = blockIdx.x * 256 + threadIdx.x;
  if (idx >= n4) return;
  float4 v = ((const float4*)src)[idx];
  unsigned short h0 = f2bf(v.x), h1 = f2bf(v.y), h2 = f2bf(v.z), h3 = f2bf(v.w);
  unsigned short e0 = f2bf(v.x - bf2f(h0)), e1 = f2bf(v.y - bf2f(h1));
  unsigned short e2 = f2bf(v.z - bf2f(h2)), e3 = f2bf(v.w - bf2f(h3));
  uint2 hv, lv;
  hv.x = (unsigned)h0 | ((unsigned)h1 << 16); hv.y = (unsigned)h2 | ((unsigned)h3 << 16);
  lv.x = (unsigned)e0 | ((unsigned)e1 << 16); lv.y = (unsigned)e2 | ((unsigned)e3 << 16);
  ((uint2*)hi)[idx] = hv;
  ((uint2*)lo)[idx] = lv;
}

// C[m][n] = sum_k A[m][k]*B[n][k] (+bias), A/B pre-split bf16 hi/lo (K-contiguous).
// 128x128 tile, BK=32, 4 waves, each wave 4x4 of 16x16x32 MFMA; 3 MFMA terms (split fp32 emu).
// LDS k-slot XOR swizzle ((row>>1)&3) keeps ds_read_b128 at 2-way bank aliasing (free).
template<int SPLIT>
__global__ __launch_bounds__(256, 2)
void mfma_gemm_nt(const unsigned short* __restrict__ Ahi, const unsigned short* __restrict__ Alo,
                  const unsigned short* __restrict__ Bhi, const unsigned short* __restrict__ Blo,
                  float* __restrict__ Cm, const float* __restrict__ bias, int K, int ldc)
{
  __shared__ __align__(16) unsigned short sAhi[4096];
  __shared__ __align__(16) unsigned short sBhi[4096];
  __shared__ __align__(16) unsigned short sAlo[4096];
  __shared__ __align__(16) unsigned short sBlo[4096];
  const int tid = threadIdx.x, lane = tid & 63, wave = tid >> 6;
  const int bm = blockIdx.y * 128, bn = blockIdx.x * 128;
  // staging: wave w, instr i covers LDS rows w*32+i*16 .. +16 (1 KiB per instr, lane*16B)
  const int srow0 = wave * 32 + (lane >> 2);
  const int srow1 = srow0 + 16;
  const int slot = lane & 3;
  const int g0 = slot ^ ((srow0 >> 1) & 3);
  const int g1 = slot ^ ((srow1 >> 1) & 3);
  const size_t aOff0 = (size_t)(bm + srow0) * K + g0 * 8;
  const size_t aOff1 = (size_t)(bm + srow1) * K + g1 * 8;
  const size_t bOff0 = (size_t)(bn + srow0) * K + g0 * 8;
  const size_t bOff1 = (size_t)(bn + srow1) * K + g1 * 8;
  const int l0 = wave * 1024, l1 = wave * 1024 + 512;   // ushort offsets (wave-uniform)
  // fragment read offsets
  const int fr = lane & 15, quad = lane >> 4;
  const int wr = (wave >> 1) * 64, wc = (wave & 1) * 64;
  int offA[4], offB[4];
#pragma unroll
  for (int i = 0; i < 4; ++i) {
    int ra = wr + i * 16 + fr;  offA[i] = ra * 32 + (quad ^ ((ra >> 1) & 3)) * 8;
    int rb = wc + i * 16 + fr;  offB[i] = rb * 32 + (quad ^ ((rb >> 1) & 3)) * 8;
  }
  f32x4 acc[4][4];
#pragma unroll
  for (int i = 0; i < 4; ++i)
#pragma unroll
    for (int j = 0; j < 4; ++j) acc[i][j] = {0.f, 0.f, 0.f, 0.f};

  for (int k0 = 0; k0 < K; k0 += 32) {
    gl2lds16(Ahi + aOff0 + k0, &sAhi[l0]);
    gl2lds16(Ahi + aOff1 + k0, &sAhi[l1]);
    gl2lds16(Bhi + bOff0 + k0, &sBhi[l0]);
    gl2lds16(Bhi + bOff1 + k0, &sBhi[l1]);
    if (SPLIT) {
      gl2lds16(Alo + aOff0 + k0, &sAlo[l0]);
      gl2lds16(Alo + aOff1 + k0, &sAlo[l1]);
      gl2lds16(Blo + bOff0 + k0, &sBlo[l0]);
      gl2lds16(Blo + bOff1 + k0, &sBlo[l1]);
    }
    __syncthreads();   // drains vmcnt -> staged tiles visible
    bf16x8 ah[4], bh[4], al[4], bl[4];
#pragma unroll
    for (int i = 0; i < 4; ++i) {
      ah[i] = *(const bf16x8*)&sAhi[offA[i]];
      bh[i] = *(const bf16x8*)&sBhi[offB[i]];
      if (SPLIT) {
        al[i] = *(const bf16x8*)&sAlo[offA[i]];
        bl[i] = *(const bf16x8*)&sBlo[offB[i]];
      }
    }
#pragma unroll
    for (int i = 0; i < 4; ++i)
#pragma unroll
      for (int j = 0; j < 4; ++j) {
        acc[i][j] = __builtin_amdgcn_mfma_f32_16x16x32_bf16(ah[i], bh[j], acc[i][j], 0, 0, 0);
        if (SPLIT) {
          acc[i][j] = __builtin_amdgcn_mfma_f32_16x16x32_bf16(ah[i], bl[j], acc[i][j], 0, 0, 0);
          acc[i][j] = __builtin_amdgcn_mfma_f32_16x16x32_bf16(al[i], bh[j], acc[i][j], 0, 0, 0);
        }
      }
    __syncthreads();   // protect LDS from next iteration's staging
  }
  // epilogue: C/D layout col=lane&15, row=quad*4+reg
#pragma unroll
  for (int j = 0; j < 4; ++j) {
    int col = bn + wc + j * 16 + fr;
    float bv = bias ? bias[col] : 0.f;
#pragma unroll
    for (int i = 0; i < 4; ++i) {
      int row0 = bm + wr + i * 16 + quad * 4;
      float* cp = Cm + (size_t)row0 * ldc + col;
#pragma unroll
      for (int r = 0; r < 4; ++r) cp[(size_t)r * ldc] = acc[i][j][r] + bv;
    }
  }
}

// Per 64-row half-chunk: tp = (t*scale) @ proj^T  [64 x 256], exact fp32 rowmax,
// exp, store bf16 to qp/kp in [chunk][s][f] layout.
__global__ __launch_bounds__(256)
void feat_kernel(const float* __restrict__ qkv, const float* __restrict__ proj,
                 unsigned short* __restrict__ qp, unsigned short* __restrict__ kp)
{
  __shared__ float As[32][68];
  __shared__ float Bs[32][260];
  __shared__ float pmax[64][33];
  __shared__ float rowmax[64];
  const int tid = threadIdx.x;
  const int half = blockIdx.x;
  const int chunk = blockIdx.y;
  const int p = blockIdx.z;
  const int b = chunk >> 8, h = (chunk >> 5) & 7, c = chunk & 31;
  const int mbase = b * N_ + c * CS_ + half * 64;
  const int colbase = p * DIM_ + h * DH_;
  const float scale = (p == 0) ? 0.125f : 1.0f;
  const int tx = tid & 31, ty = tid >> 5;

  float acc[8][8];
#pragma unroll
  for (int i = 0; i < 8; ++i)
#pragma unroll
    for (int j = 0; j < 8; ++j) acc[i][j] = 0.f;

  for (int ks = 0; ks < 64; ks += 32) {
    __syncthreads();
#pragma unroll
    for (int j = 0; j < 2; ++j) {
      int idx = tid + j * 256;
      int r = idx >> 3, dq = idx & 7;
      float4 v = *(const float4*)(qkv + (size_t)(mbase + r) * QKVC_ + colbase + ks + dq*4);
      As[dq*4+0][r] = v.x * scale; As[dq*4+1][r] = v.y * scale;
      As[dq*4+2][r] = v.z * scale; As[dq*4+3][r] = v.w * scale;
    }
#pragma unroll
    for (int j = 0; j < 8; ++j) {
      int idx = tid + j * 256;
      int f = idx >> 3, dq = idx & 7;
      float4 v = *(const float4*)(proj + (size_t)f * DH_ + ks + dq*4);
      Bs[dq*4+0][f] = v.x; Bs[dq*4+1][f] = v.y; Bs[dq*4+2][f] = v.z; Bs[dq*4+3][f] = v.w;
    }
    __syncthreads();
#pragma unroll
    for (int kk = 0; kk < 32; ++kk) {
      float a[8], bb[8];
      *(float4*)&a[0]  = *(const float4*)&As[kk][ty*4];
      *(float4*)&a[4]  = *(const float4*)&As[kk][32 + ty*4];
      *(float4*)&bb[0] = *(const float4*)&Bs[kk][tx*4];
      *(float4*)&bb[4] = *(const float4*)&Bs[kk][128 + tx*4];
#pragma unroll
      for (int i = 0; i < 8; ++i)
#pragma unroll
        for (int j = 0; j < 8; ++j)
          acc[i][j] = fmaf(a[i], bb[j], acc[i][j]);
    }
  }
#pragma unroll
  for (int i = 0; i < 8; ++i) {
    float m = acc[i][0];
#pragma unroll
    for (int j = 1; j < 8; ++j) m = fmaxf(m, acc[i][j]);
    int row = (i < 4) ? (ty*4 + i) : (32 + ty*4 + i - 4);
    pmax[row][tx] = m;
  }
  __syncthreads();
  if (tid < 64) {
    float m = pmax[tid][0];
    for (int i = 1; i < 32; ++i) m = fmaxf(m, pmax[tid][i]);
    rowmax[tid] = m;
  }
  __syncthreads();
  unsigned short* dst = ((p == 0) ? qp : kp)
                      + (size_t)chunk * (CS_ * F_) + (size_t)(half * 64) * F_;
#pragma unroll
  for (int i = 0; i < 8; ++i) {
    int row = (i < 4) ? (ty*4 + i) : (32 + ty*4 + i - 4);
    float rm = rowmax[row];
    unsigned int* w = (unsigned int*)(dst + (size_t)row * F_);
#pragma unroll
    for (int jh = 0; jh < 2; ++jh) {
      int f0 = jh*128 + tx*4;
      float v0 = __expf(acc[i][jh*4+0] - rm);
      float v1 = __expf(acc[i][jh*4+1] - rm);
      float v2 = __expf(acc[i][jh*4+2] - rm);
      float v3 = __expf(acc[i][jh*4+3] - rm);
      w[(f0 >> 1) + 0] = (unsigned int)f2bf(v0) | ((unsigned int)f2bf(v1) << 16);
      w[(f0 >> 1) + 1] = (unsigned int)f2bf(v2) | ((unsigned int)f2bf(v3) << 16);
    }
  }
}

// Per chunk: context[f][d] = sum_s kp[s][f]*v[s][d]; ksum[f] = sum_s kp[s][f].
__global__ __launch_bounds__(256)
void ctx_kernel(const float* __restrict__ qkv, const unsigned short* kp,
                float* ctx, float* __restrict__ ksum)
{
  __shared__ float vs[128][64];
  const int tid = threadIdx.x;
  const int chunk = blockIdx.x;
  const int b = chunk >> 8, h = (chunk >> 5) & 7, c = chunk & 31;
  const int mbase = b * N_ + c * CS_;
  const int vcol = 2 * DIM_ + h * DH_;
#pragma unroll
  for (int j = 0; j < 8; ++j) {
    int idx = tid + j * 256;
    int r = idx >> 4, dq = idx & 15;
    *(float4*)&vs[r][dq*4] =
        *(const float4*)(qkv + (size_t)(mbase + r) * QKVC_ + vcol + dq*4);
  }
  __syncthreads();
  const unsigned short* kpc = kp + (size_t)chunk * (CS_ * F_) + tid;
  float cacc[64];
#pragma unroll
  for (int d = 0; d < 64; ++d) cacc[d] = 0.f;
  float ks = 0.f;
#pragma unroll 4
  for (int s = 0; s < CS_; ++s) {
    float kv = bf2f(kpc[s * F_]);
    ks += kv;
#pragma unroll
    for (int dq = 0; dq < 16; ++dq) {
      float4 v4 = *(const float4*)&vs[s][dq*4];
      cacc[dq*4+0] = fmaf(kv, v4.x, cacc[dq*4+0]);
      cacc[dq*4+1] = fmaf(kv, v4.y, cacc[dq*4+1]);
      cacc[dq*4+2] = fmaf(kv, v4.z, cacc[dq*4+2]);
      cacc[dq*4+3] = fmaf(kv, v4.w, cacc[dq*4+3]);
    }
  }
  __syncthreads();
  ksum[(size_t)chunk * F_ + tid] = ks;
  float* cd = ctx + (size_t)chunk * (F_ * DH_) + (size_t)tid * DH_;
#pragma unroll
  for (int dq = 0; dq < 16; ++dq) {
    float4 o; o.x = cacc[dq*4+0]; o.y = cacc[dq*4+1]; o.z = cacc[dq*4+2]; o.w = cacc[dq*4+3];
    *(float4*)(cd + dq*4) = o;
  }
}

// Per chunk: D = qp·ksum, out = (qp @ ctx)/(D+1e-4), written as bf16 hi/lo attn [m][512].
__global__ __launch_bounds__(256)
void out_kernel(const float* __restrict__ ctx, const unsigned short* __restrict__ qp,
                const float* __restrict__ ksum,
                unsigned short* __restrict__ attn_hi, unsigned short* __restrict__ attn_lo)
{
  __shared__ float cs[F_ * DH_];
  __shared__ unsigned int qsu[16][128];
  __shared__ float ksL[F_];
  __shared__ float dred[16][17];
  __shared__ float dinv[16];
  const int tid = threadIdx.x;
  const int chunk = blockIdx.x;
  const int b = chunk >> 8, h = (chunk >> 5) & 7, c = chunk & 31;
#pragma unroll
  for (int j = 0; j < 16; ++j) {
    int idx = tid + j * 256;
    *(float4*)&cs[idx*4] = *(const float4*)(ctx + (size_t)chunk * (F_ * DH_) + idx*4);
  }
  ksL[tid] = ksum[(size_t)chunk * F_ + tid];
  const int sQ = tid >> 4;
  const int lq = tid & 15;
  for (int sl = 0; sl < 8; ++sl) {
    __syncthreads();
    const unsigned int* qsrc =
        (const unsigned int*)(qp + (size_t)chunk * (CS_ * F_) + (size_t)sl * 16 * F_);
#pragma unroll
    for (int j = 0; j < 8; ++j) {
      int idx = tid + j * 256;
      qsu[idx >> 7][idx & 127] = qsrc[idx];
    }
    __syncthreads();
    float dp = 0.f;
#pragma unroll
    for (int j = 0; j < 8; ++j) {
      unsigned int u = qsu[sQ][lq*8 + j];
      dp = fmaf(bf2f((unsigned short)(u & 0xffffu)), ksL[lq*16 + 2*j],     dp);
      dp = fmaf(bf2f((unsigned short)(u >> 16)),     ksL[lq*16 + 2*j + 1], dp);
    }
    dred[sQ][lq] = dp;
    __syncthreads();
    if (tid < 16) {
      float D = 0.f;
      for (int i = 0; i < 16; ++i) D += dred[tid][i];
      dinv[tid] = 1.f / (D + 1e-4f);
    }
    __syncthreads();
    float ox = 0.f, oy = 0.f, oz = 0.f, ow = 0.f;
    const float4* c4 = (const float4*)cs;
#pragma unroll 4
    for (int fu = 0; fu < 128; ++fu) {
      unsigned int u = qsu[sQ][fu];
      float qa = bf2f((unsigned short)(u & 0xffffu));
      float qb = bf2f((unsigned short)(u >> 16));
      float4 ca = c4[(2*fu    ) * 16 + lq];
      float4 cb = c4[(2*fu + 1) * 16 + lq];
      ox = fmaf(qa, ca.x, ox); oy = fmaf(qa, ca.y, oy);
      oz = fmaf(qa, ca.z, oz); ow = fmaf(qa, ca.w, ow);
      ox = fmaf(qb, cb.x, ox); oy = fmaf(qb, cb.y, oy);
      oz = fmaf(qb, cb.z, oz); ow = fmaf(qb, cb.w, ow);
    }
    float di = dinv[sQ];
    float vx = ox*di, vy = oy*di, vz = oz*di, vw = ow*di;
    unsigned short h0 = f2bf(vx), h1 = f2bf(vy), h2 = f2bf(vz), h3 = f2bf(vw);
    unsigned short e0 = f2bf(vx - bf2f(h0)), e1 = f2bf(vy - bf2f(h1));
    unsigned short e2 = f2bf(vz - bf2f(h2)), e3 = f2bf(vw - bf2f(h3));
    int m = b * N_ + c * CS_ + sl * 16 + sQ;
    size_t off = (size_t)m * DIM_ + h * DH_ + lq * 4;
    uint2 hv, lv;
    hv.x = (unsigned)h0 | ((unsigned)h1 << 16); hv.y = (unsigned)h2 | ((unsigned)h3 << 16);
    lv.x = (unsigned)e0 | ((unsigned)e1 << 16); lv.y = (unsigned)e2 | ((unsigned)e3 << 16);
    *(uint2*)(attn_hi + off) = hv;
    *(uint2*)(attn_lo + off) = lv;
  }
}

extern "C" void kernel_launch(void* const* d_in, const int* in_sizes, int n_in,
                              void* d_out, int out_size, void* d_ws, size_t ws_size,
                              hipStream_t stream)
{
  const float* x     = (const float*)d_in[0];
  const float* w_qkv = (const float*)d_in[1];
  const float* w_out = (const float*)d_in[2];
  const float* b_out = (const float*)d_in[3];
  const float* proj  = (const float*)d_in[4];
  float* out = (float*)d_out;

  // ws regions (total 235.9 MB):
  //   Q  = qkv fp32 [16384][1536]                  @0        100.66 MB
  //   K1 = kp bf16 [1024][128][256] (ctx aliases)  @Q end     67.11 MB
  //   K2 = qp bf16 same                            @K1 end    67.11 MB
  //   S  = ksum fp32 [1024][256]                   @K2 end     1.05 MB
  // aliases: x/wqkv splits live in K2 (dead until feat); attn hi/lo + wout
  // splits live in Q (qkv dead after ctx_kernel).
  float* qkv = (float*)d_ws;
  unsigned short* regK1 = (unsigned short*)(qkv + (size_t)M_ * QKVC_);
  unsigned short* regK2 = regK1 + (size_t)NCHUNK_ * CS_ * F_;
  float* ksum = (float*)(regK2 + (size_t)NCHUNK_ * CS_ * F_);

  unsigned short* x_hi    = regK2;
  unsigned short* x_lo    = x_hi + (size_t)M_ * DIM_;
  unsigned short* wqkv_hi = x_lo + (size_t)M_ * DIM_;
  unsigned short* wqkv_lo = wqkv_hi + (size_t)QKVC_ * DIM_;

  unsigned short* kp = regK1;
  float*          ctx = (float*)regK1;
  unsigned short* qp = regK2;

  unsigned short* attn_hi = (unsigned short*)qkv;
  unsigned short* attn_lo = attn_hi + (size_t)M_ * DIM_;
  unsigned short* wout_hi = attn_lo + (size_t)M_ * DIM_;
  unsigned short* wout_lo = wout_hi + (size_t)DIM_ * DIM_;

  // 1) fp32 -> bf16 hi/lo splits for x and w_qkv
  split_kernel<<<dim3((M_*DIM_/4 + 255)/256), 256, 0, stream>>>(x, x_hi, x_lo, M_*DIM_/4);
  split_kernel<<<dim3((QKVC_*DIM_/4 + 255)/256), 256, 0, stream>>>(w_qkv, wqkv_hi, wqkv_lo, QKVC_*DIM_/4);
  // 2) qkv = x @ w_qkv^T  (split-bf16 MFMA, fp32-grade)
  mfma_gemm_nt<1><<<dim3(QKVC_/128, M_/128), 256, 0, stream>>>(
      x_hi, x_lo, wqkv_hi, wqkv_lo, qkv, nullptr, DIM_, QKVC_);
  // 3) q' / k' features (bf16)
  feat_kernel<<<dim3(2, NCHUNK_, 2), 256, 0, stream>>>(qkv, proj, qp, kp);
  // 4) per-chunk context + ksum (ctx overwrites kp region)
  ctx_kernel<<<dim3(NCHUNK_), 256, 0, stream>>>(qkv, kp, ctx, ksum);
  // 5) per-chunk out -> attn hi/lo bf16 (overwrites qkv region; qkv dead now)
  out_kernel<<<dim3(NCHUNK_), 256, 0, stream>>>(ctx, qp, ksum, attn_hi, attn_lo);
  // 6) w_out split (into dead part of Q region)
  split_kernel<<<dim3((DIM_*DIM_/4 + 255)/256), 256, 0, stream>>>(w_out, wout_hi, wout_lo, DIM_*DIM_/4);
  // 7) out = attn @ w_out^T + b_out (split-bf16 MFMA)
  mfma_gemm_nt<1><<<dim3(DIM_/128, M_/128), 256, 0, stream>>>(
      attn_hi, attn_lo, wout_hi, wout_lo, out, b_out, DIM_, DIM_);
}

// Round 3
// 364.494 us; speedup vs baseline: 2.1684x; 1.5144x over previous
//
#include <hip/hip_runtime.h>

#define B_ 4
#define N_ 4096
#define DIM_ 512
#define H_ 8
#define DH_ 64
#define F_ 256
#define CS_ 128
#define M_ (B_*N_)         // 16384
#define NCHUNK_ 1024

typedef __attribute__((ext_vector_type(8))) short bf16x8;
typedef __attribute__((ext_vector_type(4))) float f32x4;

__device__ __forceinline__ unsigned short f2bf(float x){
  unsigned int u = __float_as_uint(x);
  u += 0x7fffu + ((u >> 16) & 1u);          // RNE
  return (unsigned short)(u >> 16);
}
__device__ __forceinline__ float bf2f(unsigned short s){
  return __uint_as_float(((unsigned int)s) << 16);
}
__device__ __forceinline__ void gl2lds16(const unsigned short* g, unsigned short* l) {
  __builtin_amdgcn_global_load_lds((const __attribute__((address_space(1))) unsigned int*)g,
                                   (__attribute__((address_space(3))) unsigned int*)l,
                                   16, 0, 0);
}

// fp32 -> bf16 hi + lo
__global__ __launch_bounds__(256)
void split_kernel(const float* __restrict__ src, unsigned short* __restrict__ hi,
                  unsigned short* __restrict__ lo, int n4)
{
  int idx = blockIdx.x * 256 + threadIdx.x;
  if (idx >= n4) return;
  float4 v = ((const float4*)src)[idx];
  unsigned short h0 = f2bf(v.x), h1 = f2bf(v.y), h2 = f2bf(v.z), h3 = f2bf(v.w);
  unsigned short e0 = f2bf(v.x - bf2f(h0)), e1 = f2bf(v.y - bf2f(h1));
  unsigned short e2 = f2bf(v.z - bf2f(h2)), e3 = f2bf(v.w - bf2f(h3));
  uint2 hv, lv;
  hv.x = (unsigned)h0 | ((unsigned)h1 << 16); hv.y = (unsigned)h2 | ((unsigned)h3 << 16);
  lv.x = (unsigned)e0 | ((unsigned)e1 << 16); lv.y = (unsigned)e2 | ((unsigned)e3 << 16);
  ((uint2*)hi)[idx] = hv;
  ((uint2*)lo)[idx] = lv;
}

// C[m][n] = sum_k A[m][k]*B[n][k]. SPLIT: 3-term bf16 emu of fp32. OUT: 0=f32(+bias), 1=bf16.
template<int SPLIT, int OUT>
__global__ __launch_bounds__(256, 2)
void mfma_gemm_nt(const unsigned short* __restrict__ Ahi, const unsigned short* __restrict__ Alo,
                  const unsigned short* __restrict__ Bhi, const unsigned short* __restrict__ Blo,
                  void* __restrict__ Cm, const float* __restrict__ bias, int K, int ldc)
{
  __shared__ __align__(16) unsigned short sAhi[4096];
  __shared__ __align__(16) unsigned short sBhi[4096];
  __shared__ __align__(16) unsigned short sAlo[4096];
  __shared__ __align__(16) unsigned short sBlo[4096];
  const int tid = threadIdx.x, lane = tid & 63, wave = tid >> 6;
  const int bm = blockIdx.y * 128, bn = blockIdx.x * 128;
  const int srow0 = wave * 32 + (lane >> 2);
  const int srow1 = srow0 + 16;
  const int slot = lane & 3;
  const int g0 = slot ^ ((srow0 >> 1) & 3);
  const int g1 = slot ^ ((srow1 >> 1) & 3);
  const size_t aOff0 = (size_t)(bm + srow0) * K + g0 * 8;
  const size_t aOff1 = (size_t)(bm + srow1) * K + g1 * 8;
  const size_t bOff0 = (size_t)(bn + srow0) * K + g0 * 8;
  const size_t bOff1 = (size_t)(bn + srow1) * K + g1 * 8;
  const int l0 = wave * 1024, l1 = wave * 1024 + 512;
  const int fr = lane & 15, quad = lane >> 4;
  const int wr = (wave >> 1) * 64, wc = (wave & 1) * 64;
  int offA[4], offB[4];
#pragma unroll
  for (int i = 0; i < 4; ++i) {
    int ra = wr + i * 16 + fr;  offA[i] = ra * 32 + (quad ^ ((ra >> 1) & 3)) * 8;
    int rb = wc + i * 16 + fr;  offB[i] = rb * 32 + (quad ^ ((rb >> 1) & 3)) * 8;
  }
  f32x4 acc[4][4];
#pragma unroll
  for (int i = 0; i < 4; ++i)
#pragma unroll
    for (int j = 0; j < 4; ++j) acc[i][j] = {0.f, 0.f, 0.f, 0.f};

  for (int k0 = 0; k0 < K; k0 += 32) {
    gl2lds16(Ahi + aOff0 + k0, &sAhi[l0]);
    gl2lds16(Ahi + aOff1 + k0, &sAhi[l1]);
    gl2lds16(Bhi + bOff0 + k0, &sBhi[l0]);
    gl2lds16(Bhi + bOff1 + k0, &sBhi[l1]);
    if (SPLIT) {
      gl2lds16(Alo + aOff0 + k0, &sAlo[l0]);
      gl2lds16(Alo + aOff1 + k0, &sAlo[l1]);
      gl2lds16(Blo + bOff0 + k0, &sBlo[l0]);
      gl2lds16(Blo + bOff1 + k0, &sBlo[l1]);
    }
    __syncthreads();
    bf16x8 ah[4], bh[4], al[4], bl[4];
#pragma unroll
    for (int i = 0; i < 4; ++i) {
      ah[i] = *(const bf16x8*)&sAhi[offA[i]];
      bh[i] = *(const bf16x8*)&sBhi[offB[i]];
      if (SPLIT) {
        al[i] = *(const bf16x8*)&sAlo[offA[i]];
        bl[i] = *(const bf16x8*)&sBlo[offB[i]];
      }
    }
#pragma unroll
    for (int i = 0; i < 4; ++i)
#pragma unroll
      for (int j = 0; j < 4; ++j) {
        acc[i][j] = __builtin_amdgcn_mfma_f32_16x16x32_bf16(ah[i], bh[j], acc[i][j], 0, 0, 0);
        if (SPLIT) {
          acc[i][j] = __builtin_amdgcn_mfma_f32_16x16x32_bf16(ah[i], bl[j], acc[i][j], 0, 0, 0);
          acc[i][j] = __builtin_amdgcn_mfma_f32_16x16x32_bf16(al[i], bh[j], acc[i][j], 0, 0, 0);
        }
      }
    __syncthreads();
  }
#pragma unroll
  for (int j = 0; j < 4; ++j) {
    int col = bn + wc + j * 16 + fr;
    float bv = (OUT == 0 && bias) ? bias[col] : 0.f;
#pragma unroll
    for (int i = 0; i < 4; ++i) {
      int row0 = bm + wr + i * 16 + quad * 4;
      if (OUT == 0) {
        float* cp = (float*)Cm + (size_t)row0 * ldc + col;
#pragma unroll
        for (int r = 0; r < 4; ++r) cp[(size_t)r * ldc] = acc[i][j][r] + bv;
      } else {
        unsigned short* cp = (unsigned short*)Cm + (size_t)row0 * ldc + col;
#pragma unroll
        for (int r = 0; r < 4; ++r) cp[(size_t)r * ldc] = f2bf(acc[i][j][r]);
      }
    }
  }
}

// Per chunk, p=0:q p=1:k. MFMA tp=(t*scale)@proj^T [128x256], fp32 rowmax, exp.
// Writes qp [s][256] swz(s&15), kpT [f][128] swz(f&15), vt hi/lo [d][128] swz(d&15), ksum.
__global__ __launch_bounds__(256, 1)
void feat_kernel(const unsigned short* __restrict__ qkv_bf, const float* __restrict__ vf,
                 const float* __restrict__ proj,
                 unsigned short* __restrict__ qp_g, unsigned short* __restrict__ kpT_g,
                 unsigned short* __restrict__ vth_g, unsigned short* __restrict__ vtl_g,
                 float* __restrict__ ksum_g)
{
  __shared__ __align__(16) char smem[151552];
  unsigned short* IN   = (unsigned short*)smem;   // [128][64] swz(s&7)   16 KB
  unsigned short* PR   = IN + 8192;               // [256][64] swz(f&7)   32 KB
  unsigned short* OUTB = PR + 16384;              // 64 KB out staging
  unsigned short* VT   = OUTB + 32768;            // 32 KB: hi 8192, lo 8192 ushorts
  float* KSP = (float*)(smem + 147456);           // [4][256]
  const int tid = threadIdx.x, lane = tid & 63, wave = tid >> 6;
  const int fr = lane & 15, quad = lane >> 4;
  const int chunk = blockIdx.x, p = blockIdx.y;
  const int b = chunk >> 8, h = (chunk >> 5) & 7, cc = chunk & 31;
  const int mbase = b * N_ + cc * CS_;
  const int colbase = p * DIM_ + h * DH_;

  // stage input tile (bf16, x0.125 for q — exact pow2 scaling)
#pragma unroll
  for (int j = 0; j < 8; ++j) {
    int idx = tid + j * 256;                 // uint2 units
    int s = idx >> 4, d0 = (idx & 15) * 4;
    uint2 v = *(const uint2*)(qkv_bf + (size_t)(mbase + s) * 1024 + colbase + d0);
    if (p == 0) {
      unsigned short e0 = f2bf(bf2f((unsigned short)(v.x & 0xffff)) * 0.125f);
      unsigned short e1 = f2bf(bf2f((unsigned short)(v.x >> 16)) * 0.125f);
      unsigned short e2 = f2bf(bf2f((unsigned short)(v.y & 0xffff)) * 0.125f);
      unsigned short e3 = f2bf(bf2f((unsigned short)(v.y >> 16)) * 0.125f);
      v.x = (unsigned)e0 | ((unsigned)e1 << 16);
      v.y = (unsigned)e2 | ((unsigned)e3 << 16);
    }
    *(uint2*)(IN + s * 64 + (((d0 >> 3) ^ (s & 7)) << 3) + (d0 & 7)) = v;
  }
  // stage proj -> bf16
#pragma unroll
  for (int j = 0; j < 16; ++j) {
    int idx = tid + j * 256;                 // float4 units
    int f = idx >> 4, d0 = (idx & 15) * 4;
    float4 v = *(const float4*)(proj + (size_t)f * 64 + d0);
    uint2 w;
    w.x = (unsigned)f2bf(v.x) | ((unsigned)f2bf(v.y) << 16);
    w.y = (unsigned)f2bf(v.z) | ((unsigned)f2bf(v.w) << 16);
    *(uint2*)(PR + f * 64 + (((d0 >> 3) ^ (f & 7)) << 3) + (d0 & 7)) = w;
  }
  __syncthreads();

  const int sw = wave * 32;
  f32x4 acc[2][16];
#pragma unroll
  for (int mt = 0; mt < 2; ++mt)
#pragma unroll
    for (int nt = 0; nt < 16; ++nt) acc[mt][nt] = {0.f, 0.f, 0.f, 0.f};
#pragma unroll
  for (int ks = 0; ks < 2; ++ks) {
    int l = ks * 4 + quad;
    bf16x8 a[2];
#pragma unroll
    for (int mt = 0; mt < 2; ++mt) {
      int row = sw + mt * 16 + fr;
      a[mt] = *(const bf16x8*)(IN + row * 64 + ((l ^ (row & 7)) << 3));
    }
#pragma unroll
    for (int nt = 0; nt < 16; ++nt) {
      int row = nt * 16 + fr;
      bf16x8 bb = *(const bf16x8*)(PR + row * 64 + ((l ^ (row & 7)) << 3));
      acc[0][nt] = __builtin_amdgcn_mfma_f32_16x16x32_bf16(a[0], bb, acc[0][nt], 0, 0, 0);
      acc[1][nt] = __builtin_amdgcn_mfma_f32_16x16x32_bf16(a[1], bb, acc[1][nt], 0, 0, 0);
    }
  }
  // exact rowmax over all 256 f, then exp
#pragma unroll
  for (int mt = 0; mt < 2; ++mt)
#pragma unroll
    for (int r = 0; r < 4; ++r) {
      float m = acc[mt][0][r];
#pragma unroll
      for (int nt = 1; nt < 16; ++nt) m = fmaxf(m, acc[mt][nt][r]);
      m = fmaxf(m, __shfl_xor(m, 1, 16));
      m = fmaxf(m, __shfl_xor(m, 2, 16));
      m = fmaxf(m, __shfl_xor(m, 4, 16));
      m = fmaxf(m, __shfl_xor(m, 8, 16));
#pragma unroll
      for (int nt = 0; nt < 16; ++nt) acc[mt][nt][r] = __expf(acc[mt][nt][r] - m);
    }
  if (p == 0) {
#pragma unroll
    for (int mt = 0; mt < 2; ++mt)
#pragma unroll
      for (int nt = 0; nt < 16; ++nt)
#pragma unroll
        for (int r = 0; r < 4; ++r) {
          int s = sw + mt * 16 + quad * 4 + r, f = nt * 16 + fr;
          OUTB[s * 256 + (((f >> 3) ^ (s & 15)) << 3) + (f & 7)] = f2bf(acc[mt][nt][r]);
        }
  } else {
#pragma unroll
    for (int mt = 0; mt < 2; ++mt)
#pragma unroll
      for (int nt = 0; nt < 16; ++nt)
#pragma unroll
        for (int r = 0; r < 4; ++r) {
          int s = sw + mt * 16 + quad * 4 + r, f = nt * 16 + fr;
          OUTB[f * 128 + (((s >> 3) ^ (f & 15)) << 3) + (s & 7)] = f2bf(acc[mt][nt][r]);
        }
    // ksum partials (fp32, pre-rounding)
#pragma unroll
    for (int nt = 0; nt < 16; ++nt) {
      float kp = 0.f;
#pragma unroll
      for (int mt = 0; mt < 2; ++mt)
#pragma unroll
        for (int r = 0; r < 4; ++r) kp += acc[mt][nt][r];
      kp += __shfl_xor(kp, 16, 64);
      kp += __shfl_xor(kp, 32, 64);
      if (quad == 0) KSP[wave * 256 + nt * 16 + fr] = kp;
    }
    // v transpose -> bf16 hi/lo
#pragma unroll
    for (int j = 0; j < 8; ++j) {
      int idx = tid + j * 256;
      int s = idx >> 4, d0 = (idx & 15) * 4;
      float4 v = *(const float4*)(vf + (size_t)(mbase + s) * 512 + h * DH_ + d0);
      float vv[4] = {v.x, v.y, v.z, v.w};
#pragma unroll
      for (int dd = 0; dd < 4; ++dd) {
        int d = d0 + dd;
        unsigned short hi = f2bf(vv[dd]);
        unsigned short lo = f2bf(vv[dd] - bf2f(hi));
        int ad = d * 128 + (((s >> 3) ^ (d & 15)) << 3) + (s & 7);
        VT[ad] = hi; VT[8192 + ad] = lo;
      }
    }
  }
  __syncthreads();
  // coalesced LDS -> global copies
  unsigned short* dst = (p == 0 ? qp_g : kpT_g) + (size_t)chunk * 32768;
#pragma unroll
  for (int j = 0; j < 16; ++j) {
    int idx = j * 256 + tid;
    *(float4*)(dst + idx * 8) = *(const float4*)(OUTB + idx * 8);
  }
  if (p == 1) {
#pragma unroll
    for (int j = 0; j < 4; ++j) {
      int idx = j * 256 + tid;
      *(float4*)(vth_g + (size_t)chunk * 8192 + idx * 8) = *(const float4*)(VT + idx * 8);
    }
#pragma unroll
    for (int j = 0; j < 4; ++j) {
      int idx = j * 256 + tid;
      *(float4*)(vtl_g + (size_t)chunk * 8192 + idx * 8) = *(const float4*)(VT + 8192 + idx * 8);
    }
    ksum_g[(size_t)chunk * 256 + tid] = KSP[tid] + KSP[256 + tid] + KSP[512 + tid] + KSP[768 + tid];
  }
}

// Fused per-chunk: ctx^T = kpT @ vt^T (v hi/lo), D = qp.ksum, out = qp @ ctx (ctx hi/lo).
__global__ __launch_bounds__(256, 1)
void chunk_kernel(const unsigned short* __restrict__ kpT_g, const unsigned short* __restrict__ qp_g,
                  const unsigned short* __restrict__ vth_g, const unsigned short* __restrict__ vtl_g,
                  const float* __restrict__ ksum_g,
                  unsigned short* __restrict__ attn_hi, unsigned short* __restrict__ attn_lo)
{
  __shared__ __align__(16) char smem[163840];
  unsigned short* LDS = (unsigned short*)smem;
  // ushort idx: [0,32768) kpT -> later ctx_hi@0, ctx_lo@16384
  //             [32768,49152) vt_hi@32768, vt_lo@40960 -> later ksum/dinv (bytes 65536..)
  //             [49152,81920) qp
  float* KS = (float*)(smem + 65536);
  float* DI = (float*)(smem + 66560);
  const int tid = threadIdx.x, lane = tid & 63, wave = tid >> 6;
  const int fr = lane & 15, quad = lane >> 4;
  const int chunk = blockIdx.x;
  const int b = chunk >> 8, h = (chunk >> 5) & 7, cc = chunk & 31;
  const int lofs = lane * 8;
  const unsigned short* kps = kpT_g + (size_t)chunk * 32768;
  const unsigned short* qps = qp_g + (size_t)chunk * 32768;
  const unsigned short* vhs = vth_g + (size_t)chunk * 8192;
  const unsigned short* vls = vtl_g + (size_t)chunk * 8192;
#pragma unroll
  for (int i = 0; i < 16; ++i) gl2lds16(kps + (wave*16+i)*512 + lofs, LDS + (wave*16+i)*512);
#pragma unroll
  for (int i = 0; i < 4; ++i)  gl2lds16(vhs + (wave*4+i)*512 + lofs, LDS + 32768 + (wave*4+i)*512);
#pragma unroll
  for (int i = 0; i < 4; ++i)  gl2lds16(vls + (wave*4+i)*512 + lofs, LDS + 40960 + (wave*4+i)*512);
  __syncthreads();
  // async prefetch qp during step A
#pragma unroll
  for (int i = 0; i < 16; ++i) gl2lds16(qps + (wave*16+i)*512 + lofs, LDS + 49152 + (wave*16+i)*512);

  // Step A: ctx^T[f][d]-ish: C[m=f][n=d] = sum_s kpT[f][s]*vt[d][s]
  f32x4 acc[4][4];
#pragma unroll
  for (int i = 0; i < 4; ++i)
#pragma unroll
    for (int j = 0; j < 4; ++j) acc[i][j] = {0.f, 0.f, 0.f, 0.f};
#pragma unroll
  for (int ks = 0; ks < 4; ++ks) {
    int l = ks * 4 + quad;
    bf16x8 a[4];
#pragma unroll
    for (int mt = 0; mt < 4; ++mt) {
      int f = wave * 64 + mt * 16 + fr;
      a[mt] = *(const bf16x8*)(LDS + f * 128 + ((l ^ (f & 15)) << 3));
    }
#pragma unroll
    for (int nt = 0; nt < 4; ++nt) {
      int d = nt * 16 + fr;
      bf16x8 bh = *(const bf16x8*)(LDS + 32768 + d * 128 + ((l ^ (d & 15)) << 3));
      bf16x8 bl = *(const bf16x8*)(LDS + 40960 + d * 128 + ((l ^ (d & 15)) << 3));
#pragma unroll
      for (int mt = 0; mt < 4; ++mt) {
        acc[mt][nt] = __builtin_amdgcn_mfma_f32_16x16x32_bf16(a[mt], bh, acc[mt][nt], 0, 0, 0);
        acc[mt][nt] = __builtin_amdgcn_mfma_f32_16x16x32_bf16(a[mt], bl, acc[mt][nt], 0, 0, 0);
      }
    }
  }
  __syncthreads();     // qp staged; kpT/vt reads complete
  KS[tid] = ksum_g[(size_t)chunk * 256 + tid];
  // ctx -> LDS (hi/lo), overwriting kpT region
#pragma unroll
  for (int mt = 0; mt < 4; ++mt)
#pragma unroll
    for (int nt = 0; nt < 4; ++nt)
#pragma unroll
      for (int r = 0; r < 4; ++r) {
        int f = wave * 64 + mt * 16 + quad * 4 + r;
        int d = nt * 16 + fr;
        float v = acc[mt][nt][r];
        unsigned short hi = f2bf(v);
        unsigned short lo = f2bf(v - bf2f(hi));
        int ad = d * 256 + (((f >> 3) ^ (d & 15)) << 3) + (f & 7);
        LDS[ad] = hi; LDS[16384 + ad] = lo;
      }
  __syncthreads();
  // D = qp . ksum
  if (tid < 128) {
    int s = tid;
    float dp = 0.f;
#pragma unroll 4
    for (int l = 0; l < 32; ++l) {
      bf16x8 qv = *(const bf16x8*)(LDS + 49152 + s * 256 + ((l ^ (s & 15)) << 3));
      f32x4 k0 = *(const f32x4*)(KS + l * 8);
      f32x4 k1 = *(const f32x4*)(KS + l * 8 + 4);
      dp += bf2f((unsigned short)qv[0]) * k0[0];
      dp += bf2f((unsigned short)qv[1]) * k0[1];
      dp += bf2f((unsigned short)qv[2]) * k0[2];
      dp += bf2f((unsigned short)qv[3]) * k0[3];
      dp += bf2f((unsigned short)qv[4]) * k1[0];
      dp += bf2f((unsigned short)qv[5]) * k1[1];
      dp += bf2f((unsigned short)qv[6]) * k1[2];
      dp += bf2f((unsigned short)qv[7]) * k1[3];
    }
    DI[s] = 1.f / (dp + 1e-4f);
  }
  __syncthreads();
  // Step B: C[m=s][n=d] = sum_f qp[s][f]*ctx[d-row][f]
  f32x4 acc2[2][4];
#pragma unroll
  for (int i = 0; i < 2; ++i)
#pragma unroll
    for (int j = 0; j < 4; ++j) acc2[i][j] = {0.f, 0.f, 0.f, 0.f};
#pragma unroll
  for (int ks = 0; ks < 8; ++ks) {
    int l = ks * 4 + quad;
    bf16x8 a[2];
#pragma unroll
    for (int mt = 0; mt < 2; ++mt) {
      int s = wave * 32 + mt * 16 + fr;
      a[mt] = *(const bf16x8*)(LDS + 49152 + s * 256 + ((l ^ (s & 15)) << 3));
    }
#pragma unroll
    for (int nt = 0; nt < 4; ++nt) {
      int d = nt * 16 + fr;
      bf16x8 bh = *(const bf16x8*)(LDS + d * 256 + ((l ^ (d & 15)) << 3));
      bf16x8 bl = *(const bf16x8*)(LDS + 16384 + d * 256 + ((l ^ (d & 15)) << 3));
#pragma unroll
      for (int mt = 0; mt < 2; ++mt) {
        acc2[mt][nt] = __builtin_amdgcn_mfma_f32_16x16x32_bf16(a[mt], bh, acc2[mt][nt], 0, 0, 0);
        acc2[mt][nt] = __builtin_amdgcn_mfma_f32_16x16x32_bf16(a[mt], bl, acc2[mt][nt], 0, 0, 0);
      }
    }
  }
  // epilogue: scale by dinv, split hi/lo, store attn
#pragma unroll
  for (int mt = 0; mt < 2; ++mt)
#pragma unroll
    for (int nt = 0; nt < 4; ++nt)
#pragma unroll
      for (int r = 0; r < 4; ++r) {
        int s = wave * 32 + mt * 16 + quad * 4 + r;
        int d = nt * 16 + fr;
        float v = acc2[mt][nt][r] * DI[s];
        unsigned short hi = f2bf(v);
        unsigned short lo = f2bf(v - bf2f(hi));
        size_t off = (size_t)(b * N_ + cc * CS_ + s) * 512 + h * DH_ + d;
        attn_hi[off] = hi; attn_lo[off] = lo;
      }
}

extern "C" void kernel_launch(void* const* d_in, const int* in_sizes, int n_in,
                              void* d_out, int out_size, void* d_ws, size_t ws_size,
                              hipStream_t stream)
{
  const float* x     = (const float*)d_in[0];
  const float* w_qkv = (const float*)d_in[1];
  const float* w_out = (const float*)d_in[2];
  const float* b_out = (const float*)d_in[3];
  const float* proj  = (const float*)d_in[4];
  float* out = (float*)d_out;

  // ws layout (235,929,600 B total):
  //  R0 @0:          qkv_bf bf16 [16384][1024] (q,k)   33,554,432   -> later attn_hi/attn_lo
  //  R1 @33554432:   v_f32 [16384][512]                33,554,432   -> later wout_hi/lo
  //  R2 @67108864:   qp_g bf16 [1024][128][256]        67,108,864   (x/wqkv splits live here pre-feat)
  //  R3 @134217728:  kpT_g bf16 [1024][256][128]       67,108,864
  //  R4 @201326592:  vt_hi, vt_lo bf16 [1024][64][128] 33,554,432
  //  R5 @234881024:  ksum f32 [1024][256]               1,048,576
  char* ws = (char*)d_ws;
  unsigned short* qkv_bf = (unsigned short*)ws;
  float*          v_f32  = (float*)(ws + 33554432);
  unsigned short* qp_g   = (unsigned short*)(ws + 67108864);
  unsigned short* kpT_g  = (unsigned short*)(ws + 134217728);
  unsigned short* vth_g  = (unsigned short*)(ws + 201326592);
  unsigned short* vtl_g  = (unsigned short*)(ws + 218103808);
  float*          ksum_g = (float*)(ws + 234881024);

  unsigned short* x_hi    = qp_g;                                  // dead before feat writes qp
  unsigned short* x_lo    = x_hi + (size_t)M_ * DIM_;
  unsigned short* wqkv_hi = x_lo + (size_t)M_ * DIM_;
  unsigned short* wqkv_lo = wqkv_hi + (size_t)(3*DIM_) * DIM_;

  unsigned short* attn_hi = qkv_bf;                                // qkv_bf dead after feat
  unsigned short* attn_lo = attn_hi + (size_t)M_ * DIM_;
  unsigned short* wout_hi = (unsigned short*)v_f32;                // v_f32 dead after feat
  unsigned short* wout_lo = wout_hi + (size_t)DIM_ * DIM_;

  // 1) splits
  split_kernel<<<dim3(M_*DIM_/4/256), 256, 0, stream>>>(x, x_hi, x_lo, M_*DIM_/4);
  split_kernel<<<dim3(3*DIM_*DIM_/4/256), 256, 0, stream>>>(w_qkv, wqkv_hi, wqkv_lo, 3*DIM_*DIM_/4);
  // 2) q,k = x @ w_qkv[0:1024]^T  (single bf16, bf16 out)
  mfma_gemm_nt<0,1><<<dim3(8, M_/128), 256, 0, stream>>>(
      x_hi, x_hi, wqkv_hi, wqkv_hi, qkv_bf, nullptr, DIM_, 1024);
  // 3) v = x @ w_qkv[1024:1536]^T (split, fp32 out)
  mfma_gemm_nt<1,0><<<dim3(4, M_/128), 256, 0, stream>>>(
      x_hi, x_lo, wqkv_hi + (size_t)1024*DIM_, wqkv_lo + (size_t)1024*DIM_,
      v_f32, nullptr, DIM_, DIM_);
  // 4) features + transposes + ksum
  feat_kernel<<<dim3(NCHUNK_, 2), 256, 0, stream>>>(qkv_bf, v_f32, proj,
                                                    qp_g, kpT_g, vth_g, vtl_g, ksum_g);
  // 5) fused ctx + D + out per chunk
  chunk_kernel<<<dim3(NCHUNK_), 256, 0, stream>>>(kpT_g, qp_g, vth_g, vtl_g, ksum_g,
                                                  attn_hi, attn_lo);
  // 6) w_out split, then out = attn @ w_out^T + b_out (split)
  split_kernel<<<dim3(DIM_*DIM_/4/256), 256, 0, stream>>>(w_out, wout_hi, wout_lo, DIM_*DIM_/4);
  mfma_gemm_nt<1,0><<<dim3(4, M_/128), 256, 0, stream>>>(
      attn_hi, attn_lo, wout_hi, wout_lo, out, b_out, DIM_, DIM_);
}

// Round 4
// 300.225 us; speedup vs baseline: 2.6326x; 1.2141x over previous
//
#include <hip/hip_runtime.h>

#define B_ 4
#define N_ 4096
#define DIM_ 512
#define H_ 8
#define DH_ 64
#define F_ 256
#define CS_ 128
#define M_ (B_*N_)         // 16384
#define NCHUNK_ 1024

typedef __attribute__((ext_vector_type(8))) short bf16x8;
typedef __attribute__((ext_vector_type(4))) float f32x4;

__device__ __forceinline__ unsigned short f2bf(float x){
  unsigned int u = __float_as_uint(x);
  u += 0x7fffu + ((u >> 16) & 1u);          // RNE
  return (unsigned short)(u >> 16);
}
__device__ __forceinline__ float bf2f(unsigned short s){
  return __uint_as_float(((unsigned int)s) << 16);
}
__device__ __forceinline__ unsigned pack2(float a, float b){
  return (unsigned)f2bf(a) | ((unsigned)f2bf(b) << 16);
}
__device__ __forceinline__ void gl2lds16(const unsigned short* g, unsigned short* l) {
  __builtin_amdgcn_global_load_lds((const __attribute__((address_space(1))) unsigned int*)g,
                                   (__attribute__((address_space(3))) unsigned int*)l,
                                   16, 0, 0);
}

// fp32 -> bf16 hi + lo
__global__ __launch_bounds__(256)
void split_kernel(const float* __restrict__ src, unsigned short* __restrict__ hi,
                  unsigned short* __restrict__ lo, int n4)
{
  int idx = blockIdx.x * 256 + threadIdx.x;
  if (idx >= n4) return;
  float4 v = ((const float4*)src)[idx];
  unsigned short h0 = f2bf(v.x), h1 = f2bf(v.y), h2 = f2bf(v.z), h3 = f2bf(v.w);
  unsigned short e0 = f2bf(v.x - bf2f(h0)), e1 = f2bf(v.y - bf2f(h1));
  unsigned short e2 = f2bf(v.z - bf2f(h2)), e3 = f2bf(v.w - bf2f(h3));
  uint2 hv, lv;
  hv.x = (unsigned)h0 | ((unsigned)h1 << 16); hv.y = (unsigned)h2 | ((unsigned)h3 << 16);
  lv.x = (unsigned)e0 | ((unsigned)e1 << 16); lv.y = (unsigned)e2 | ((unsigned)e3 << 16);
  ((uint2*)hi)[idx] = hv;
  ((uint2*)lo)[idx] = lv;
}

// proj fp32 [256][64] -> projk bf16, projq bf16 (pre-scaled by 0.125, exact pow2)
__global__ __launch_bounds__(256)
void prep_proj(const float* __restrict__ proj, unsigned short* __restrict__ pq,
               unsigned short* __restrict__ pk)
{
  int idx = blockIdx.x * 256 + threadIdx.x;   // float4 idx, 4096 total
  if (idx >= 4096) return;
  float4 v = ((const float4*)proj)[idx];
  uint2 k, q;
  k.x = pack2(v.x, v.y);           k.y = pack2(v.z, v.w);
  q.x = pack2(v.x*0.125f, v.y*0.125f); q.y = pack2(v.z*0.125f, v.w*0.125f);
  ((uint2*)pk)[idx] = k;
  ((uint2*)pq)[idx] = q;
}

// C[m][n] = sum_k A[m][k]*B[n][k]. SPLIT: 3-term bf16 emu of fp32.
// OUT: 0=f32(+bias), 1=bf16, 2=v-transpose hi/lo split into vth/vtl (swizzled chunk layout).
template<int SPLIT, int OUT>
__global__ __launch_bounds__(256, 2)
void mfma_gemm_nt(const unsigned short* __restrict__ Ahi, const unsigned short* __restrict__ Alo,
                  const unsigned short* __restrict__ Bhi, const unsigned short* __restrict__ Blo,
                  void* __restrict__ Cm, const float* __restrict__ bias, int K, int ldc,
                  unsigned short* __restrict__ vth, unsigned short* __restrict__ vtl)
{
  __shared__ __align__(16) unsigned short sAhi[4096];
  __shared__ __align__(16) unsigned short sBhi[4096];
  __shared__ __align__(16) unsigned short sAlo[4096];
  __shared__ __align__(16) unsigned short sBlo[4096];
  const int tid = threadIdx.x, lane = tid & 63, wave = tid >> 6;
  const int bm = blockIdx.y * 128, bn = blockIdx.x * 128;
  const int srow0 = wave * 32 + (lane >> 2);
  const int srow1 = srow0 + 16;
  const int slot = lane & 3;
  const int g0 = slot ^ ((srow0 >> 1) & 3);
  const int g1 = slot ^ ((srow1 >> 1) & 3);
  const size_t aOff0 = (size_t)(bm + srow0) * K + g0 * 8;
  const size_t aOff1 = (size_t)(bm + srow1) * K + g1 * 8;
  const size_t bOff0 = (size_t)(bn + srow0) * K + g0 * 8;
  const size_t bOff1 = (size_t)(bn + srow1) * K + g1 * 8;
  const int l0 = wave * 1024, l1 = wave * 1024 + 512;
  const int fr = lane & 15, quad = lane >> 4;
  const int wr = (wave >> 1) * 64, wc = (wave & 1) * 64;
  int offA[4], offB[4];
#pragma unroll
  for (int i = 0; i < 4; ++i) {
    int ra = wr + i * 16 + fr;  offA[i] = ra * 32 + (quad ^ ((ra >> 1) & 3)) * 8;
    int rb = wc + i * 16 + fr;  offB[i] = rb * 32 + (quad ^ ((rb >> 1) & 3)) * 8;
  }
  f32x4 acc[4][4];
#pragma unroll
  for (int i = 0; i < 4; ++i)
#pragma unroll
    for (int j = 0; j < 4; ++j) acc[i][j] = {0.f, 0.f, 0.f, 0.f};

  for (int k0 = 0; k0 < K; k0 += 32) {
    gl2lds16(Ahi + aOff0 + k0, &sAhi[l0]);
    gl2lds16(Ahi + aOff1 + k0, &sAhi[l1]);
    gl2lds16(Bhi + bOff0 + k0, &sBhi[l0]);
    gl2lds16(Bhi + bOff1 + k0, &sBhi[l1]);
    if (SPLIT) {
      gl2lds16(Alo + aOff0 + k0, &sAlo[l0]);
      gl2lds16(Alo + aOff1 + k0, &sAlo[l1]);
      gl2lds16(Blo + bOff0 + k0, &sBlo[l0]);
      gl2lds16(Blo + bOff1 + k0, &sBlo[l1]);
    }
    __syncthreads();
    bf16x8 ah[4], bh[4], al[4], bl[4];
#pragma unroll
    for (int i = 0; i < 4; ++i) {
      ah[i] = *(const bf16x8*)&sAhi[offA[i]];
      bh[i] = *(const bf16x8*)&sBhi[offB[i]];
      if (SPLIT) {
        al[i] = *(const bf16x8*)&sAlo[offA[i]];
        bl[i] = *(const bf16x8*)&sBlo[offB[i]];
      }
    }
#pragma unroll
    for (int i = 0; i < 4; ++i)
#pragma unroll
      for (int j = 0; j < 4; ++j) {
        acc[i][j] = __builtin_amdgcn_mfma_f32_16x16x32_bf16(ah[i], bh[j], acc[i][j], 0, 0, 0);
        if (SPLIT) {
          acc[i][j] = __builtin_amdgcn_mfma_f32_16x16x32_bf16(ah[i], bl[j], acc[i][j], 0, 0, 0);
          acc[i][j] = __builtin_amdgcn_mfma_f32_16x16x32_bf16(al[i], bh[j], acc[i][j], 0, 0, 0);
        }
      }
    __syncthreads();
  }
#pragma unroll
  for (int j = 0; j < 4; ++j) {
    int col = bn + wc + j * 16 + fr;
    float bv = (OUT == 0 && bias) ? bias[col] : 0.f;
#pragma unroll
    for (int i = 0; i < 4; ++i) {
      int row0 = bm + wr + i * 16 + quad * 4;
      if (OUT == 0) {
        float* cp = (float*)Cm + (size_t)row0 * ldc + col;
#pragma unroll
        for (int r = 0; r < 4; ++r) cp[(size_t)r * ldc] = acc[i][j][r] + bv;
      } else if (OUT == 1) {
        unsigned short* cp = (unsigned short*)Cm + (size_t)row0 * ldc + col;
#pragma unroll
        for (int r = 0; r < 4; ++r) cp[(size_t)r * ldc] = f2bf(acc[i][j][r]);
      } else {
        // v-transpose: col = d_global, rows = 4 consecutive tokens (= consecutive s)
        int hh = col >> 6, d = col & 63;
        int bb = row0 >> 12, cc2 = (row0 >> 7) & 31, s = row0 & 127;
        int ck = bb * 256 + hh * 32 + cc2;
        size_t ad = (size_t)ck * 8192 + d * 128 + (((s >> 3) ^ (d & 15)) << 3) + (s & 7);
        float v0 = acc[i][j][0], v1 = acc[i][j][1], v2 = acc[i][j][2], v3 = acc[i][j][3];
        unsigned short h0 = f2bf(v0), h1 = f2bf(v1), h2 = f2bf(v2), h3 = f2bf(v3);
        uint2 hv, lv;
        hv.x = (unsigned)h0 | ((unsigned)h1 << 16);
        hv.y = (unsigned)h2 | ((unsigned)h3 << 16);
        lv.x = pack2(v0 - bf2f(h0), v1 - bf2f(h1));
        lv.y = pack2(v2 - bf2f(h2), v3 - bf2f(h3));
        *(uint2*)(vth + ad) = hv;
        *(uint2*)(vtl + ad) = lv;
      }
    }
  }
}

// Per chunk, p=0: q-pass computes C[f][s] (proj as A-operand); p=1: k-pass C[s][f].
// Outputs packed uint2, staged through one 32 KB bounce, coalesced to global.
// qp_g [s][256f swz(f>>3 ^ s&15)], kpT_g [f][128s swz(s>>3 ^ f&15)], ksum fp32.
__global__ __launch_bounds__(256, 2)
void feat_kernel(const unsigned short* __restrict__ qkv_bf,
                 const unsigned short* __restrict__ projq,
                 const unsigned short* __restrict__ projk,
                 unsigned short* __restrict__ qp_g, unsigned short* __restrict__ kpT_g,
                 float* __restrict__ ksum_g)
{
  __shared__ __align__(16) unsigned short IN[8192];      // [128 s][64 d] granule^(s&7)  16 KB
  __shared__ __align__(16) unsigned short BOUNCE[16384]; // 32 KB staging
  __shared__ float KSP[4][256];                          // 4 KB (k-pass)
  const int tid = threadIdx.x, lane = tid & 63, wave = tid >> 6;
  const int fr = lane & 15, quad = lane >> 4;
  const int chunk = blockIdx.x, p = blockIdx.y;
  const int b = chunk >> 8, h = (chunk >> 5) & 7, cc = chunk & 31;
  const int mbase = b * N_ + cc * CS_;
  const int colbase = p * DIM_ + h * DH_;

  // stage t tile (coalesced uint2)
#pragma unroll
  for (int j = 0; j < 8; ++j) {
    int idx = tid + j * 256;                 // uint2 units
    int s = idx >> 4, d0 = (idx & 15) * 4;
    uint2 v = *(const uint2*)(qkv_bf + (size_t)(mbase + s) * 1024 + colbase + d0);
    *(uint2*)(IN + s * 64 + (((d0 >> 3) ^ (s & 7)) << 3) + (d0 & 7)) = v;
  }
  __syncthreads();

  if (p == 0) {
    // ---- q-pass: C[m=f][n=s], A = projq (global), B = t (IN) ----
    f32x4 acc[16][2];
#pragma unroll
    for (int mt = 0; mt < 16; ++mt) { acc[mt][0] = {0,0,0,0}; acc[mt][1] = {0,0,0,0}; }
#pragma unroll
    for (int ks = 0; ks < 2; ++ks) {
      bf16x8 bfr[2];
#pragma unroll
      for (int nt = 0; nt < 2; ++nt) {
        int s = wave * 32 + nt * 16 + fr;
        bfr[nt] = *(const bf16x8*)(IN + s * 64 + (((ks * 4 + quad) ^ (s & 7)) << 3));
      }
#pragma unroll
      for (int mt = 0; mt < 16; ++mt) {
        bf16x8 af = *(const bf16x8*)(projq + (size_t)(mt * 16 + fr) * 64 + ks * 32 + quad * 8);
        acc[mt][0] = __builtin_amdgcn_mfma_f32_16x16x32_bf16(af, bfr[0], acc[mt][0], 0, 0, 0);
        acc[mt][1] = __builtin_amdgcn_mfma_f32_16x16x32_bf16(af, bfr[1], acc[mt][1], 0, 0, 0);
      }
    }
    // rowmax over f (in-lane mt,r then cross-quad), exp
#pragma unroll
    for (int nt = 0; nt < 2; ++nt) {
      float m = -1e30f;
#pragma unroll
      for (int mt = 0; mt < 16; ++mt)
#pragma unroll
        for (int r = 0; r < 4; ++r) m = fmaxf(m, acc[mt][nt][r]);
      m = fmaxf(m, __shfl_xor(m, 16, 64));
      m = fmaxf(m, __shfl_xor(m, 32, 64));
#pragma unroll
      for (int mt = 0; mt < 16; ++mt)
#pragma unroll
        for (int r = 0; r < 4; ++r) acc[mt][nt][r] = __expf(acc[mt][nt][r] - m);
    }
    // stage + copy in s-halves (waves 0,1 own s 0..63; waves 2,3 own 64..127)
    unsigned short* dst = qp_g + (size_t)chunk * 32768;
#pragma unroll
    for (int hf = 0; hf < 2; ++hf) {
      if ((wave >> 1) == hf) {
#pragma unroll
        for (int nt = 0; nt < 2; ++nt) {
          int sl = (wave & 1) * 32 + nt * 16 + fr;   // local row in half
#pragma unroll
          for (int mt = 0; mt < 16; ++mt) {
            int g = mt * 2 + (quad >> 1);            // f>>3
            uint2 w;
            w.x = pack2(acc[mt][nt][0], acc[mt][nt][1]);
            w.y = pack2(acc[mt][nt][2], acc[mt][nt][3]);
            *(uint2*)(BOUNCE + sl * 256 + ((g ^ fr) << 3) + (quad & 1) * 4) = w;
          }
        }
      }
      __syncthreads();
#pragma unroll
      for (int j2 = 0; j2 < 8; ++j2) {
        int idx = j2 * 256 + tid;
        *(float4*)(dst + (size_t)hf * 16384 + idx * 8) = *(const float4*)(BOUNCE + idx * 8);
      }
      __syncthreads();
    }
  } else {
    // ---- k-pass: C[m=s][n=f], A = t (IN), B = projk (global) ----
    f32x4 acc[2][16];
#pragma unroll
    for (int nt = 0; nt < 16; ++nt) { acc[0][nt] = {0,0,0,0}; acc[1][nt] = {0,0,0,0}; }
#pragma unroll
    for (int ks = 0; ks < 2; ++ks) {
      bf16x8 a[2];
#pragma unroll
      for (int mt = 0; mt < 2; ++mt) {
        int s = wave * 32 + mt * 16 + fr;
        a[mt] = *(const bf16x8*)(IN + s * 64 + (((ks * 4 + quad) ^ (s & 7)) << 3));
      }
#pragma unroll
      for (int nt = 0; nt < 16; ++nt) {
        bf16x8 bf = *(const bf16x8*)(projk + (size_t)(nt * 16 + fr) * 64 + ks * 32 + quad * 8);
        acc[0][nt] = __builtin_amdgcn_mfma_f32_16x16x32_bf16(a[0], bf, acc[0][nt], 0, 0, 0);
        acc[1][nt] = __builtin_amdgcn_mfma_f32_16x16x32_bf16(a[1], bf, acc[1][nt], 0, 0, 0);
      }
    }
    // rowmax per (mt,r) over f (in-lane nt, cross-fr), exp
#pragma unroll
    for (int mt = 0; mt < 2; ++mt)
#pragma unroll
      for (int r = 0; r < 4; ++r) {
        float m = acc[mt][0][r];
#pragma unroll
        for (int nt = 1; nt < 16; ++nt) m = fmaxf(m, acc[mt][nt][r]);
        m = fmaxf(m, __shfl_xor(m, 1, 16));
        m = fmaxf(m, __shfl_xor(m, 2, 16));
        m = fmaxf(m, __shfl_xor(m, 4, 16));
        m = fmaxf(m, __shfl_xor(m, 8, 16));
#pragma unroll
        for (int nt = 0; nt < 16; ++nt) acc[mt][nt][r] = __expf(acc[mt][nt][r] - m);
      }
    // ksum partials per f (pre-rounding fp32)
#pragma unroll
    for (int nt = 0; nt < 16; ++nt) {
      float sm = 0.f;
#pragma unroll
      for (int mt = 0; mt < 2; ++mt)
#pragma unroll
        for (int r = 0; r < 4; ++r) sm += acc[mt][nt][r];
      sm += __shfl_xor(sm, 16, 64);
      sm += __shfl_xor(sm, 32, 64);
      if (quad == 0) KSP[wave][nt * 16 + fr] = sm;
    }
    // stage + copy kpT in f-halves (all waves each half)
    unsigned short* dst = kpT_g + (size_t)chunk * 32768;
#pragma unroll
    for (int hf = 0; hf < 2; ++hf) {
#pragma unroll
      for (int nt2 = 0; nt2 < 8; ++nt2) {
        int nt = hf * 8 + nt2;
        int frow = (nt2 * 16 + fr);                  // f & 127
#pragma unroll
        for (int mt = 0; mt < 2; ++mt) {
          int g = wave * 4 + mt * 2 + (quad >> 1);   // s>>3
          uint2 w;
          w.x = pack2(acc[mt][nt][0], acc[mt][nt][1]);
          w.y = pack2(acc[mt][nt][2], acc[mt][nt][3]);
          *(uint2*)(BOUNCE + frow * 128 + ((g ^ fr) << 3) + (quad & 1) * 4) = w;
        }
      }
      __syncthreads();
#pragma unroll
      for (int j2 = 0; j2 < 8; ++j2) {
        int idx = j2 * 256 + tid;
        *(float4*)(dst + (size_t)hf * 16384 + idx * 8) = *(const float4*)(BOUNCE + idx * 8);
      }
      __syncthreads();
    }
    ksum_g[(size_t)chunk * 256 + tid] = KSP[0][tid] + KSP[1][tid] + KSP[2][tid] + KSP[3][tid];
  }
}

// Fused per-chunk: ctx^T = kpT @ vt^T (v hi/lo), D = qp.ksum, out = qp @ ctx (ctx hi/lo).
__global__ __launch_bounds__(256, 1)
void chunk_kernel(const unsigned short* __restrict__ kpT_g, const unsigned short* __restrict__ qp_g,
                  const unsigned short* __restrict__ vth_g, const unsigned short* __restrict__ vtl_g,
                  const float* __restrict__ ksum_g,
                  unsigned short* __restrict__ attn_hi, unsigned short* __restrict__ attn_lo)
{
  __shared__ __align__(16) char smem[163840];
  unsigned short* LDS = (unsigned short*)smem;
  float* KS = (float*)(smem + 65536);
  float* DI = (float*)(smem + 66560);
  const int tid = threadIdx.x, lane = tid & 63, wave = tid >> 6;
  const int fr = lane & 15, quad = lane >> 4;
  const int chunk = blockIdx.x;
  const int b = chunk >> 8, h = (chunk >> 5) & 7, cc = chunk & 31;
  const int lofs = lane * 8;
  const unsigned short* kps = kpT_g + (size_t)chunk * 32768;
  const unsigned short* qps = qp_g + (size_t)chunk * 32768;
  const unsigned short* vhs = vth_g + (size_t)chunk * 8192;
  const unsigned short* vls = vtl_g + (size_t)chunk * 8192;
#pragma unroll
  for (int i = 0; i < 16; ++i) gl2lds16(kps + (wave*16+i)*512 + lofs, LDS + (wave*16+i)*512);
#pragma unroll
  for (int i = 0; i < 4; ++i)  gl2lds16(vhs + (wave*4+i)*512 + lofs, LDS + 32768 + (wave*4+i)*512);
#pragma unroll
  for (int i = 0; i < 4; ++i)  gl2lds16(vls + (wave*4+i)*512 + lofs, LDS + 40960 + (wave*4+i)*512);
  __syncthreads();
#pragma unroll
  for (int i = 0; i < 16; ++i) gl2lds16(qps + (wave*16+i)*512 + lofs, LDS + 49152 + (wave*16+i)*512);

  f32x4 acc[4][4];
#pragma unroll
  for (int i = 0; i < 4; ++i)
#pragma unroll
    for (int j = 0; j < 4; ++j) acc[i][j] = {0.f, 0.f, 0.f, 0.f};
#pragma unroll
  for (int ks = 0; ks < 4; ++ks) {
    int l = ks * 4 + quad;
    bf16x8 a[4];
#pragma unroll
    for (int mt = 0; mt < 4; ++mt) {
      int f = wave * 64 + mt * 16 + fr;
      a[mt] = *(const bf16x8*)(LDS + f * 128 + ((l ^ (f & 15)) << 3));
    }
#pragma unroll
    for (int nt = 0; nt < 4; ++nt) {
      int d = nt * 16 + fr;
      bf16x8 bh = *(const bf16x8*)(LDS + 32768 + d * 128 + ((l ^ (d & 15)) << 3));
      bf16x8 bl = *(const bf16x8*)(LDS + 40960 + d * 128 + ((l ^ (d & 15)) << 3));
#pragma unroll
      for (int mt = 0; mt < 4; ++mt) {
        acc[mt][nt] = __builtin_amdgcn_mfma_f32_16x16x32_bf16(a[mt], bh, acc[mt][nt], 0, 0, 0);
        acc[mt][nt] = __builtin_amdgcn_mfma_f32_16x16x32_bf16(a[mt], bl, acc[mt][nt], 0, 0, 0);
      }
    }
  }
  __syncthreads();
  KS[tid] = ksum_g[(size_t)chunk * 256 + tid];
#pragma unroll
  for (int mt = 0; mt < 4; ++mt)
#pragma unroll
    for (int nt = 0; nt < 4; ++nt)
#pragma unroll
      for (int r = 0; r < 4; ++r) {
        int f = wave * 64 + mt * 16 + quad * 4 + r;
        int d = nt * 16 + fr;
        float v = acc[mt][nt][r];
        unsigned short hi = f2bf(v);
        unsigned short lo = f2bf(v - bf2f(hi));
        int ad = d * 256 + (((f >> 3) ^ (d & 15)) << 3) + (f & 7);
        LDS[ad] = hi; LDS[16384 + ad] = lo;
      }
  __syncthreads();
  if (tid < 128) {
    int s = tid;
    float dp = 0.f;
#pragma unroll 4
    for (int l = 0; l < 32; ++l) {
      bf16x8 qv = *(const bf16x8*)(LDS + 49152 + s * 256 + ((l ^ (s & 15)) << 3));
      f32x4 k0 = *(const f32x4*)(KS + l * 8);
      f32x4 k1 = *(const f32x4*)(KS + l * 8 + 4);
      dp += bf2f((unsigned short)qv[0]) * k0[0];
      dp += bf2f((unsigned short)qv[1]) * k0[1];
      dp += bf2f((unsigned short)qv[2]) * k0[2];
      dp += bf2f((unsigned short)qv[3]) * k0[3];
      dp += bf2f((unsigned short)qv[4]) * k1[0];
      dp += bf2f((unsigned short)qv[5]) * k1[1];
      dp += bf2f((unsigned short)qv[6]) * k1[2];
      dp += bf2f((unsigned short)qv[7]) * k1[3];
    }
    DI[s] = 1.f / (dp + 1e-4f);
  }
  __syncthreads();
  f32x4 acc2[2][4];
#pragma unroll
  for (int i = 0; i < 2; ++i)
#pragma unroll
    for (int j = 0; j < 4; ++j) acc2[i][j] = {0.f, 0.f, 0.f, 0.f};
#pragma unroll
  for (int ks = 0; ks < 8; ++ks) {
    int l = ks * 4 + quad;
    bf16x8 a[2];
#pragma unroll
    for (int mt = 0; mt < 2; ++mt) {
      int s = wave * 32 + mt * 16 + fr;
      a[mt] = *(const bf16x8*)(LDS + 49152 + s * 256 + ((l ^ (s & 15)) << 3));
    }
#pragma unroll
    for (int nt = 0; nt < 4; ++nt) {
      int d = nt * 16 + fr;
      bf16x8 bh = *(const bf16x8*)(LDS + d * 256 + ((l ^ (d & 15)) << 3));
      bf16x8 bl = *(const bf16x8*)(LDS + 16384 + d * 256 + ((l ^ (d & 15)) << 3));
#pragma unroll
      for (int mt = 0; mt < 2; ++mt) {
        acc2[mt][nt] = __builtin_amdgcn_mfma_f32_16x16x32_bf16(a[mt], bh, acc2[mt][nt], 0, 0, 0);
        acc2[mt][nt] = __builtin_amdgcn_mfma_f32_16x16x32_bf16(a[mt], bl, acc2[mt][nt], 0, 0, 0);
      }
    }
  }
#pragma unroll
  for (int mt = 0; mt < 2; ++mt)
#pragma unroll
    for (int nt = 0; nt < 4; ++nt)
#pragma unroll
      for (int r = 0; r < 4; ++r) {
        int s = wave * 32 + mt * 16 + quad * 4 + r;
        int d = nt * 16 + fr;
        float v = acc2[mt][nt][r] * DI[s];
        unsigned short hi = f2bf(v);
        unsigned short lo = f2bf(v - bf2f(hi));
        size_t off = (size_t)(b * N_ + cc * CS_ + s) * 512 + h * DH_ + d;
        attn_hi[off] = hi; attn_lo[off] = lo;
      }
}

extern "C" void kernel_launch(void* const* d_in, const int* in_sizes, int n_in,
                              void* d_out, int out_size, void* d_ws, size_t ws_size,
                              hipStream_t stream)
{
  const float* x     = (const float*)d_in[0];
  const float* w_qkv = (const float*)d_in[1];
  const float* w_out = (const float*)d_in[2];
  const float* b_out = (const float*)d_in[3];
  const float* proj  = (const float*)d_in[4];
  float* out = (float*)d_out;

  // ws layout (235,929,600 B total):
  //  R0 @0:          qkv_bf bf16 [16384][1024] (q,k)   33,554,432  -> later attn_hi/lo
  //  R1 @33554432:   x_hi/x_lo bf16 [16384][512] each  33,554,432  -> later projq/projk + wout splits
  //  R2 @67108864:   qp_g bf16 [1024][128][256]        67,108,864  (wqkv splits live here pre-feat)
  //  R3 @134217728:  kpT_g bf16 [1024][256][128]       67,108,864
  //  R4 @201326592:  vt_hi, vt_lo bf16 [1024][64][128] 33,554,432  (written by gemm_v epilogue)
  //  R5 @234881024:  ksum f32 [1024][256]               1,048,576
  char* ws = (char*)d_ws;
  unsigned short* qkv_bf = (unsigned short*)ws;
  unsigned short* x_hi   = (unsigned short*)(ws + 33554432);
  unsigned short* x_lo   = x_hi + (size_t)M_ * DIM_;
  unsigned short* qp_g   = (unsigned short*)(ws + 67108864);
  unsigned short* kpT_g  = (unsigned short*)(ws + 134217728);
  unsigned short* vth_g  = (unsigned short*)(ws + 201326592);
  unsigned short* vtl_g  = (unsigned short*)(ws + 218103808);
  float*          ksum_g = (float*)(ws + 234881024);

  unsigned short* wqkv_hi = qp_g;                       // dead before feat writes qp
  unsigned short* wqkv_lo = wqkv_hi + (size_t)(3*DIM_) * DIM_;

  unsigned short* projq = x_hi;                         // x splits dead after gemm_v
  unsigned short* projk = projq + 16384;
  unsigned short* wout_hi = projk + 16384;
  unsigned short* wout_lo = wout_hi + (size_t)DIM_ * DIM_;

  unsigned short* attn_hi = qkv_bf;                     // qkv_bf dead after feat
  unsigned short* attn_lo = attn_hi + (size_t)M_ * DIM_;

  // 1) splits
  split_kernel<<<dim3(M_*DIM_/4/256), 256, 0, stream>>>(x, x_hi, x_lo, M_*DIM_/4);
  split_kernel<<<dim3(3*DIM_*DIM_/4/256), 256, 0, stream>>>(w_qkv, wqkv_hi, wqkv_lo, 3*DIM_*DIM_/4);
  // 2) q,k = x @ w_qkv[0:1024]^T  (single bf16, bf16 out)
  mfma_gemm_nt<0,1><<<dim3(8, M_/128), 256, 0, stream>>>(
      x_hi, x_hi, wqkv_hi, wqkv_hi, qkv_bf, nullptr, DIM_, 1024, nullptr, nullptr);
  // 3) v = x @ w_qkv[1024:1536]^T (split) -> transposed hi/lo chunk layout directly
  mfma_gemm_nt<1,2><<<dim3(4, M_/128), 256, 0, stream>>>(
      x_hi, x_lo, wqkv_hi + (size_t)1024*DIM_, wqkv_lo + (size_t)1024*DIM_,
      nullptr, nullptr, DIM_, 0, vth_g, vtl_g);
  // 4) proj -> bf16 (q pre-scaled by 1/8); x splits dead now
  prep_proj<<<dim3(16), 256, 0, stream>>>(proj, projq, projk);
  // 5) features (q-pass / k-pass)
  feat_kernel<<<dim3(NCHUNK_, 2), 256, 0, stream>>>(qkv_bf, projq, projk,
                                                    qp_g, kpT_g, ksum_g);
  // 6) fused ctx + D + out per chunk
  chunk_kernel<<<dim3(NCHUNK_), 256, 0, stream>>>(kpT_g, qp_g, vth_g, vtl_g, ksum_g,
                                                  attn_hi, attn_lo);
  // 7) w_out split, then out = attn @ w_out^T + b_out (split)
  split_kernel<<<dim3(DIM_*DIM_/4/256), 256, 0, stream>>>(w_out, wout_hi, wout_lo, DIM_*DIM_/4);
  mfma_gemm_nt<1,0><<<dim3(4, M_/128), 256, 0, stream>>>(
      attn_hi, attn_lo, wout_hi, wout_lo, out, b_out, DIM_, DIM_, nullptr, nullptr);
}

// Round 5
// 281.652 us; speedup vs baseline: 2.8062x; 1.0659x over previous
//
#include <hip/hip_runtime.h>

#define B_ 4
#define N_ 4096
#define DIM_ 512
#define H_ 8
#define DH_ 64
#define F_ 256
#define CS_ 128
#define M_ (B_*N_)         // 16384
#define NCHUNK_ 1024

typedef __attribute__((ext_vector_type(8))) short bf16x8;
typedef __attribute__((ext_vector_type(4))) float f32x4;

__device__ __forceinline__ unsigned short f2bf(float x){
  unsigned int u = __float_as_uint(x);
  u += 0x7fffu + ((u >> 16) & 1u);          // RNE
  return (unsigned short)(u >> 16);
}
__device__ __forceinline__ float bf2f(unsigned short s){
  return __uint_as_float(((unsigned int)s) << 16);
}
__device__ __forceinline__ unsigned pack2(float a, float b){
  return (unsigned)f2bf(a) | ((unsigned)f2bf(b) << 16);
}
__device__ __forceinline__ void gl2lds16(const unsigned short* g, unsigned short* l) {
  __builtin_amdgcn_global_load_lds((const __attribute__((address_space(1))) unsigned int*)g,
                                   (__attribute__((address_space(3))) unsigned int*)l,
                                   16, 0, 0);
}

// fp32 -> bf16 hi + lo
__global__ __launch_bounds__(256)
void split_kernel(const float* __restrict__ src, unsigned short* __restrict__ hi,
                  unsigned short* __restrict__ lo, int n4)
{
  int idx = blockIdx.x * 256 + threadIdx.x;
  if (idx >= n4) return;
  float4 v = ((const float4*)src)[idx];
  unsigned short h0 = f2bf(v.x), h1 = f2bf(v.y), h2 = f2bf(v.z), h3 = f2bf(v.w);
  unsigned short e0 = f2bf(v.x - bf2f(h0)), e1 = f2bf(v.y - bf2f(h1));
  unsigned short e2 = f2bf(v.z - bf2f(h2)), e3 = f2bf(v.w - bf2f(h3));
  uint2 hv, lv;
  hv.x = (unsigned)h0 | ((unsigned)h1 << 16); hv.y = (unsigned)h2 | ((unsigned)h3 << 16);
  lv.x = (unsigned)e0 | ((unsigned)e1 << 16); lv.y = (unsigned)e2 | ((unsigned)e3 << 16);
  ((uint2*)hi)[idx] = hv;
  ((uint2*)lo)[idx] = lv;
}

// proj fp32 [256][64] -> projk bf16, projq bf16 (pre-scaled by 0.125, exact pow2)
__global__ __launch_bounds__(256)
void prep_proj(const float* __restrict__ proj, unsigned short* __restrict__ pq,
               unsigned short* __restrict__ pk)
{
  int idx = blockIdx.x * 256 + threadIdx.x;   // float4 idx, 4096 total
  if (idx >= 4096) return;
  float4 v = ((const float4*)proj)[idx];
  uint2 k, q;
  k.x = pack2(v.x, v.y);           k.y = pack2(v.z, v.w);
  q.x = pack2(v.x*0.125f, v.y*0.125f); q.y = pack2(v.z*0.125f, v.w*0.125f);
  ((uint2*)pk)[idx] = k;
  ((uint2*)pq)[idx] = q;
}

// C[m][n] = sum_k A[m][k]*B[n][k]. SPLIT: 3-term bf16 emu of fp32.
// OUT: 0=f32(+bias), 1=bf16, 2=v-transpose hi/lo split into vth/vtl (swizzled chunk layout).
template<int SPLIT, int OUT>
__global__ __launch_bounds__(256, 2)
void mfma_gemm_nt(const unsigned short* __restrict__ Ahi, const unsigned short* __restrict__ Alo,
                  const unsigned short* __restrict__ Bhi, const unsigned short* __restrict__ Blo,
                  void* __restrict__ Cm, const float* __restrict__ bias, int K, int ldc,
                  unsigned short* __restrict__ vth, unsigned short* __restrict__ vtl)
{
  __shared__ __align__(16) unsigned short sAhi[4096];
  __shared__ __align__(16) unsigned short sBhi[4096];
  __shared__ __align__(16) unsigned short sAlo[4096];
  __shared__ __align__(16) unsigned short sBlo[4096];
  const int tid = threadIdx.x, lane = tid & 63, wave = tid >> 6;
  const int bm = blockIdx.y * 128, bn = blockIdx.x * 128;
  const int srow0 = wave * 32 + (lane >> 2);
  const int srow1 = srow0 + 16;
  const int slot = lane & 3;
  const int g0 = slot ^ ((srow0 >> 1) & 3);
  const int g1 = slot ^ ((srow1 >> 1) & 3);
  const size_t aOff0 = (size_t)(bm + srow0) * K + g0 * 8;
  const size_t aOff1 = (size_t)(bm + srow1) * K + g1 * 8;
  const size_t bOff0 = (size_t)(bn + srow0) * K + g0 * 8;
  const size_t bOff1 = (size_t)(bn + srow1) * K + g1 * 8;
  const int l0 = wave * 1024, l1 = wave * 1024 + 512;
  const int fr = lane & 15, quad = lane >> 4;
  const int wr = (wave >> 1) * 64, wc = (wave & 1) * 64;
  int offA[4], offB[4];
#pragma unroll
  for (int i = 0; i < 4; ++i) {
    int ra = wr + i * 16 + fr;  offA[i] = ra * 32 + (quad ^ ((ra >> 1) & 3)) * 8;
    int rb = wc + i * 16 + fr;  offB[i] = rb * 32 + (quad ^ ((rb >> 1) & 3)) * 8;
  }
  f32x4 acc[4][4];
#pragma unroll
  for (int i = 0; i < 4; ++i)
#pragma unroll
    for (int j = 0; j < 4; ++j) acc[i][j] = {0.f, 0.f, 0.f, 0.f};

  for (int k0 = 0; k0 < K; k0 += 32) {
    gl2lds16(Ahi + aOff0 + k0, &sAhi[l0]);
    gl2lds16(Ahi + aOff1 + k0, &sAhi[l1]);
    gl2lds16(Bhi + bOff0 + k0, &sBhi[l0]);
    gl2lds16(Bhi + bOff1 + k0, &sBhi[l1]);
    if (SPLIT) {
      gl2lds16(Alo + aOff0 + k0, &sAlo[l0]);
      gl2lds16(Alo + aOff1 + k0, &sAlo[l1]);
      gl2lds16(Blo + bOff0 + k0, &sBlo[l0]);
      gl2lds16(Blo + bOff1 + k0, &sBlo[l1]);
    }
    __syncthreads();
    bf16x8 ah[4], bh[4], al[4], bl[4];
#pragma unroll
    for (int i = 0; i < 4; ++i) {
      ah[i] = *(const bf16x8*)&sAhi[offA[i]];
      bh[i] = *(const bf16x8*)&sBhi[offB[i]];
      if (SPLIT) {
        al[i] = *(const bf16x8*)&sAlo[offA[i]];
        bl[i] = *(const bf16x8*)&sBlo[offB[i]];
      }
    }
#pragma unroll
    for (int i = 0; i < 4; ++i)
#pragma unroll
      for (int j = 0; j < 4; ++j) {
        acc[i][j] = __builtin_amdgcn_mfma_f32_16x16x32_bf16(ah[i], bh[j], acc[i][j], 0, 0, 0);
        if (SPLIT) {
          acc[i][j] = __builtin_amdgcn_mfma_f32_16x16x32_bf16(ah[i], bl[j], acc[i][j], 0, 0, 0);
          acc[i][j] = __builtin_amdgcn_mfma_f32_16x16x32_bf16(al[i], bh[j], acc[i][j], 0, 0, 0);
        }
      }
    __syncthreads();
  }
#pragma unroll
  for (int j = 0; j < 4; ++j) {
    int col = bn + wc + j * 16 + fr;
    float bv = (OUT == 0 && bias) ? bias[col] : 0.f;
#pragma unroll
    for (int i = 0; i < 4; ++i) {
      int row0 = bm + wr + i * 16 + quad * 4;
      if (OUT == 0) {
        float* cp = (float*)Cm + (size_t)row0 * ldc + col;
#pragma unroll
        for (int r = 0; r < 4; ++r) cp[(size_t)r * ldc] = acc[i][j][r] + bv;
      } else if (OUT == 1) {
        unsigned short* cp = (unsigned short*)Cm + (size_t)row0 * ldc + col;
#pragma unroll
        for (int r = 0; r < 4; ++r) cp[(size_t)r * ldc] = f2bf(acc[i][j][r]);
      } else {
        // v-transpose: col = d_global, rows = 4 consecutive tokens (= consecutive s)
        int hh = col >> 6, d = col & 63;
        int bb = row0 >> 12, cc2 = (row0 >> 7) & 31, s = row0 & 127;
        int ck = bb * 256 + hh * 32 + cc2;
        size_t ad = (size_t)ck * 8192 + d * 128 + (((s >> 3) ^ (d & 15)) << 3) + (s & 7);
        float v0 = acc[i][j][0], v1 = acc[i][j][1], v2 = acc[i][j][2], v3 = acc[i][j][3];
        unsigned short h0 = f2bf(v0), h1 = f2bf(v1), h2 = f2bf(v2), h3 = f2bf(v3);
        uint2 hv, lv;
        hv.x = (unsigned)h0 | ((unsigned)h1 << 16);
        hv.y = (unsigned)h2 | ((unsigned)h3 << 16);
        lv.x = pack2(v0 - bf2f(h0), v1 - bf2f(h1));
        lv.y = pack2(v2 - bf2f(h2), v3 - bf2f(h3));
        *(uint2*)(vth + ad) = hv;
        *(uint2*)(vtl + ad) = lv;
      }
    }
  }
}

// Fully fused per-chunk Performer kernel: k-pass -> q-pass -> ctx (2 vt passes)
// -> D -> out. All intermediates (kpT, qp, ctx, ksum) stay in LDS.
__global__ __launch_bounds__(256, 1)
void fused_chunk(const unsigned short* __restrict__ qkv_bf,
                 const unsigned short* __restrict__ projq,
                 const unsigned short* __restrict__ projk,
                 const unsigned short* __restrict__ vth_g,
                 const unsigned short* __restrict__ vtl_g,
                 unsigned short* __restrict__ attn_hi,
                 unsigned short* __restrict__ attn_lo)
{
  __shared__ __align__(16) char smem[153088];
  unsigned short* KPT = (unsigned short*)smem;            // [256 f][128 s] swz -> later ctx hi/lo
  unsigned short* QP  = (unsigned short*)(smem + 65536);  // [128 s][256 f] swz
  unsigned short* X   = (unsigned short*)(smem + 131072); // 16 KB bounce: t_k / t_q / vth / vtl
  float* KS  = (float*)(smem + 147456);                   // [256]
  float* DI  = (float*)(smem + 148480);                   // [128]
  float* KSP = (float*)(smem + 148992);                   // [4][256]

  const int tid = threadIdx.x, lane = tid & 63, wave = tid >> 6;
  const int fr = lane & 15, quad = lane >> 4;
  const int chunk = blockIdx.x;
  const int b = chunk >> 8, h = (chunk >> 5) & 7, cc = chunk & 31;
  const int mbase = b * N_ + cc * CS_;

  // ---- phase 1: stage t_k into X ----
#pragma unroll
  for (int j = 0; j < 8; ++j) {
    int idx = tid + j * 256;                 // uint2 units
    int s = idx >> 4, d0 = (idx & 15) * 4;
    uint2 v = *(const uint2*)(qkv_bf + (size_t)(mbase + s) * 1024 + 512 + h * DH_ + d0);
    *(uint2*)(X + s * 64 + (((d0 >> 3) ^ (s & 7)) << 3) + (d0 & 7)) = v;
  }
  __syncthreads();

  // ---- phase 2: k-pass: C[s][f] = t_k @ projk^T, rowmax, exp, write kpT + KSP ----
  {
    f32x4 ka[2][16];
#pragma unroll
    for (int nt = 0; nt < 16; ++nt) { ka[0][nt] = {0,0,0,0}; ka[1][nt] = {0,0,0,0}; }
#pragma unroll
    for (int ks = 0; ks < 2; ++ks) {
      bf16x8 a[2];
#pragma unroll
      for (int mt = 0; mt < 2; ++mt) {
        int s = wave * 32 + mt * 16 + fr;
        a[mt] = *(const bf16x8*)(X + s * 64 + (((ks * 4 + quad) ^ (s & 7)) << 3));
      }
#pragma unroll
      for (int nt = 0; nt < 16; ++nt) {
        bf16x8 bf = *(const bf16x8*)(projk + (size_t)(nt * 16 + fr) * 64 + ks * 32 + quad * 8);
        ka[0][nt] = __builtin_amdgcn_mfma_f32_16x16x32_bf16(a[0], bf, ka[0][nt], 0, 0, 0);
        ka[1][nt] = __builtin_amdgcn_mfma_f32_16x16x32_bf16(a[1], bf, ka[1][nt], 0, 0, 0);
      }
    }
#pragma unroll
    for (int mt = 0; mt < 2; ++mt)
#pragma unroll
      for (int r = 0; r < 4; ++r) {
        float m = ka[mt][0][r];
#pragma unroll
        for (int nt = 1; nt < 16; ++nt) m = fmaxf(m, ka[mt][nt][r]);
        m = fmaxf(m, __shfl_xor(m, 1, 16));
        m = fmaxf(m, __shfl_xor(m, 2, 16));
        m = fmaxf(m, __shfl_xor(m, 4, 16));
        m = fmaxf(m, __shfl_xor(m, 8, 16));
#pragma unroll
        for (int nt = 0; nt < 16; ++nt) ka[mt][nt][r] = __expf(ka[mt][nt][r] - m);
      }
    // ksum partials
#pragma unroll
    for (int nt = 0; nt < 16; ++nt) {
      float sm = 0.f;
#pragma unroll
      for (int mt = 0; mt < 2; ++mt)
#pragma unroll
        for (int r = 0; r < 4; ++r) sm += ka[mt][nt][r];
      sm += __shfl_xor(sm, 16, 64);
      sm += __shfl_xor(sm, 32, 64);
      if (quad == 0) KSP[wave * 256 + nt * 16 + fr] = sm;
    }
    // kpT[f][s] write (4 consecutive s per lane)
#pragma unroll
    for (int nt = 0; nt < 16; ++nt) {
      int f = nt * 16 + fr;
#pragma unroll
      for (int mt = 0; mt < 2; ++mt) {
        int g = wave * 4 + mt * 2 + (quad >> 1);     // s>>3
        uint2 w;
        w.x = pack2(ka[mt][nt][0], ka[mt][nt][1]);
        w.y = pack2(ka[mt][nt][2], ka[mt][nt][3]);
        *(uint2*)(KPT + f * 128 + ((g ^ (f & 15)) << 3) + (quad & 1) * 4) = w;
      }
    }
  }
  __syncthreads();

  // ---- phase 3: KS reduce + stage t_q into X ----
  KS[tid] = KSP[tid] + KSP[256 + tid] + KSP[512 + tid] + KSP[768 + tid];
#pragma unroll
  for (int j = 0; j < 8; ++j) {
    int idx = tid + j * 256;
    int s = idx >> 4, d0 = (idx & 15) * 4;
    uint2 v = *(const uint2*)(qkv_bf + (size_t)(mbase + s) * 1024 + h * DH_ + d0);
    *(uint2*)(X + s * 64 + (((d0 >> 3) ^ (s & 7)) << 3) + (d0 & 7)) = v;
  }
  __syncthreads();

  // ---- phase 4: q-pass: C[f][s] = projq @ t_q^T, colmax(f), exp, write qp ----
  {
    f32x4 qa[16][2];
#pragma unroll
    for (int mt = 0; mt < 16; ++mt) { qa[mt][0] = {0,0,0,0}; qa[mt][1] = {0,0,0,0}; }
#pragma unroll
    for (int ks = 0; ks < 2; ++ks) {
      bf16x8 bfr[2];
#pragma unroll
      for (int nt = 0; nt < 2; ++nt) {
        int s = wave * 32 + nt * 16 + fr;
        bfr[nt] = *(const bf16x8*)(X + s * 64 + (((ks * 4 + quad) ^ (s & 7)) << 3));
      }
#pragma unroll
      for (int mt = 0; mt < 16; ++mt) {
        bf16x8 af = *(const bf16x8*)(projq + (size_t)(mt * 16 + fr) * 64 + ks * 32 + quad * 8);
        qa[mt][0] = __builtin_amdgcn_mfma_f32_16x16x32_bf16(af, bfr[0], qa[mt][0], 0, 0, 0);
        qa[mt][1] = __builtin_amdgcn_mfma_f32_16x16x32_bf16(af, bfr[1], qa[mt][1], 0, 0, 0);
      }
    }
#pragma unroll
    for (int nt = 0; nt < 2; ++nt) {
      float m = -1e30f;
#pragma unroll
      for (int mt = 0; mt < 16; ++mt)
#pragma unroll
        for (int r = 0; r < 4; ++r) m = fmaxf(m, qa[mt][nt][r]);
      m = fmaxf(m, __shfl_xor(m, 16, 64));
      m = fmaxf(m, __shfl_xor(m, 32, 64));
#pragma unroll
      for (int mt = 0; mt < 16; ++mt)
#pragma unroll
        for (int r = 0; r < 4; ++r) qa[mt][nt][r] = __expf(qa[mt][nt][r] - m);
    }
    // qp[s][f] write (4 consecutive f per lane)
#pragma unroll
    for (int nt = 0; nt < 2; ++nt) {
      int s = wave * 32 + nt * 16 + fr;
#pragma unroll
      for (int mt = 0; mt < 16; ++mt) {
        int g = mt * 2 + (quad >> 1);               // f>>3
        uint2 w;
        w.x = pack2(qa[mt][nt][0], qa[mt][nt][1]);
        w.y = pack2(qa[mt][nt][2], qa[mt][nt][3]);
        *(uint2*)(QP + s * 256 + ((g ^ (s & 15)) << 3) + (quad & 1) * 4) = w;
      }
    }
  }
  __syncthreads();

  // ---- phase 5: step A, pass 1 (v hi): ctx[f][d] += kpT @ vth^T ----
  const unsigned short* vhs = vth_g + (size_t)chunk * 8192;
  const unsigned short* vls = vtl_g + (size_t)chunk * 8192;
#pragma unroll
  for (int i = 0; i < 4; ++i) gl2lds16(vhs + (wave*4+i)*512 + lane*8, X + (wave*4+i)*512);
  __syncthreads();

  f32x4 acc_a[4][4];
#pragma unroll
  for (int i = 0; i < 4; ++i)
#pragma unroll
    for (int j = 0; j < 4; ++j) acc_a[i][j] = {0.f, 0.f, 0.f, 0.f};
#pragma unroll
  for (int ks = 0; ks < 4; ++ks) {
    int l = ks * 4 + quad;
    bf16x8 a[4];
#pragma unroll
    for (int mt = 0; mt < 4; ++mt) {
      int f = wave * 64 + mt * 16 + fr;
      a[mt] = *(const bf16x8*)(KPT + f * 128 + ((l ^ (f & 15)) << 3));
    }
#pragma unroll
    for (int nt = 0; nt < 4; ++nt) {
      int d = nt * 16 + fr;
      bf16x8 bh = *(const bf16x8*)(X + d * 128 + ((l ^ (d & 15)) << 3));
#pragma unroll
      for (int mt = 0; mt < 4; ++mt)
        acc_a[mt][nt] = __builtin_amdgcn_mfma_f32_16x16x32_bf16(a[mt], bh, acc_a[mt][nt], 0, 0, 0);
    }
  }
  __syncthreads();
  // ---- phase 6: step A, pass 2 (v lo) ----
#pragma unroll
  for (int i = 0; i < 4; ++i) gl2lds16(vls + (wave*4+i)*512 + lane*8, X + (wave*4+i)*512);
  __syncthreads();
#pragma unroll
  for (int ks = 0; ks < 4; ++ks) {
    int l = ks * 4 + quad;
    bf16x8 a[4];
#pragma unroll
    for (int mt = 0; mt < 4; ++mt) {
      int f = wave * 64 + mt * 16 + fr;
      a[mt] = *(const bf16x8*)(KPT + f * 128 + ((l ^ (f & 15)) << 3));
    }
#pragma unroll
    for (int nt = 0; nt < 4; ++nt) {
      int d = nt * 16 + fr;
      bf16x8 bl = *(const bf16x8*)(X + d * 128 + ((l ^ (d & 15)) << 3));
#pragma unroll
      for (int mt = 0; mt < 4; ++mt)
        acc_a[mt][nt] = __builtin_amdgcn_mfma_f32_16x16x32_bf16(a[mt], bl, acc_a[mt][nt], 0, 0, 0);
    }
  }
  __syncthreads();   // all kpT reads done before ctx overwrites it

  // ---- phase 7: ctx hi/lo -> LDS over KPT region ([64 d][256 f], hi@0, lo@16384) ----
#pragma unroll
  for (int mt = 0; mt < 4; ++mt)
#pragma unroll
    for (int nt = 0; nt < 4; ++nt) {
      int f0 = wave * 64 + mt * 16 + quad * 4;
      int d = nt * 16 + fr;
      int g = wave * 8 + mt * 2 + (quad >> 1);      // f>>3
      float v0 = acc_a[mt][nt][0], v1 = acc_a[mt][nt][1];
      float v2 = acc_a[mt][nt][2], v3 = acc_a[mt][nt][3];
      unsigned short h0 = f2bf(v0), h1 = f2bf(v1), h2 = f2bf(v2), h3 = f2bf(v3);
      uint2 whi, wlo;
      whi.x = (unsigned)h0 | ((unsigned)h1 << 16);
      whi.y = (unsigned)h2 | ((unsigned)h3 << 16);
      wlo.x = pack2(v0 - bf2f(h0), v1 - bf2f(h1));
      wlo.y = pack2(v2 - bf2f(h2), v3 - bf2f(h3));
      int ad = d * 256 + ((g ^ (d & 15)) << 3) + (quad & 1) * 4;
      *(uint2*)(KPT + ad) = whi;
      *(uint2*)(KPT + 16384 + ad) = wlo;
      (void)f0;
    }
  __syncthreads();

  // ---- phase 8: D = qp . ksum ----
  if (tid < 128) {
    int s = tid;
    float dp = 0.f;
#pragma unroll 4
    for (int l = 0; l < 32; ++l) {
      bf16x8 qv = *(const bf16x8*)(QP + s * 256 + ((l ^ (s & 15)) << 3));
      f32x4 k0 = *(const f32x4*)(KS + l * 8);
      f32x4 k1 = *(const f32x4*)(KS + l * 8 + 4);
      dp += bf2f((unsigned short)qv[0]) * k0[0];
      dp += bf2f((unsigned short)qv[1]) * k0[1];
      dp += bf2f((unsigned short)qv[2]) * k0[2];
      dp += bf2f((unsigned short)qv[3]) * k0[3];
      dp += bf2f((unsigned short)qv[4]) * k1[0];
      dp += bf2f((unsigned short)qv[5]) * k1[1];
      dp += bf2f((unsigned short)qv[6]) * k1[2];
      dp += bf2f((unsigned short)qv[7]) * k1[3];
    }
    DI[s] = 1.f / (dp + 1e-4f);
  }
  __syncthreads();

  // ---- phase 9: step B: C[m=d][n=s] = sum_f ctx[d][f]*qp[s][f]; scale; store ----
  f32x4 acc2[4][2];
#pragma unroll
  for (int i = 0; i < 4; ++i) { acc2[i][0] = {0,0,0,0}; acc2[i][1] = {0,0,0,0}; }
#pragma unroll
  for (int ks = 0; ks < 8; ++ks) {
    int l = ks * 4 + quad;
    bf16x8 ah[4], al[4];
#pragma unroll
    for (int mt = 0; mt < 4; ++mt) {
      int d = mt * 16 + fr;
      int ad = d * 256 + ((l ^ (d & 15)) << 3);
      ah[mt] = *(const bf16x8*)(KPT + ad);
      al[mt] = *(const bf16x8*)(KPT + 16384 + ad);
    }
#pragma unroll
    for (int nt = 0; nt < 2; ++nt) {
      int s = wave * 32 + nt * 16 + fr;
      bf16x8 bq = *(const bf16x8*)(QP + s * 256 + ((l ^ (s & 15)) << 3));
#pragma unroll
      for (int mt = 0; mt < 4; ++mt) {
        acc2[mt][nt] = __builtin_amdgcn_mfma_f32_16x16x32_bf16(ah[mt], bq, acc2[mt][nt], 0, 0, 0);
        acc2[mt][nt] = __builtin_amdgcn_mfma_f32_16x16x32_bf16(al[mt], bq, acc2[mt][nt], 0, 0, 0);
      }
    }
  }
#pragma unroll
  for (int nt = 0; nt < 2; ++nt) {
    int s = wave * 32 + nt * 16 + fr;
    float di = DI[s];
    size_t base = (size_t)(mbase + s) * 512 + h * DH_;
#pragma unroll
    for (int mt = 0; mt < 4; ++mt) {
      int d0 = mt * 16 + quad * 4;
      float o0 = acc2[mt][nt][0] * di, o1 = acc2[mt][nt][1] * di;
      float o2 = acc2[mt][nt][2] * di, o3 = acc2[mt][nt][3] * di;
      unsigned short h0 = f2bf(o0), h1 = f2bf(o1), h2 = f2bf(o2), h3 = f2bf(o3);
      uint2 whi, wlo;
      whi.x = (unsigned)h0 | ((unsigned)h1 << 16);
      whi.y = (unsigned)h2 | ((unsigned)h3 << 16);
      wlo.x = pack2(o0 - bf2f(h0), o1 - bf2f(h1));
      wlo.y = pack2(o2 - bf2f(h2), o3 - bf2f(h3));
      *(uint2*)(attn_hi + base + d0) = whi;
      *(uint2*)(attn_lo + base + d0) = wlo;
    }
  }
}

extern "C" void kernel_launch(void* const* d_in, const int* in_sizes, int n_in,
                              void* d_out, int out_size, void* d_ws, size_t ws_size,
                              hipStream_t stream)
{
  const float* x     = (const float*)d_in[0];
  const float* w_qkv = (const float*)d_in[1];
  const float* w_out = (const float*)d_in[2];
  const float* b_out = (const float*)d_in[3];
  const float* proj  = (const float*)d_in[4];
  float* out = (float*)d_out;

  // ws layout (235,929,600 B total):
  //  R0 @0:          qkv_bf bf16 [16384][1024] (q,k)   33,554,432
  //  R1 @33554432:   x_hi/x_lo bf16 [16384][512] each  33,554,432  -> later projq/projk + wout splits
  //  R2 @67108864:   wqkv splits (3 MB)                            (rest free)
  //  R3 @134217728:  attn_hi, attn_lo bf16 [16384][512] 33,554,432
  //  R4 @201326592:  vt_hi, vt_lo bf16 [1024][64][128] 33,554,432  (written by gemm_v epilogue)
  char* ws = (char*)d_ws;
  unsigned short* qkv_bf = (unsigned short*)ws;
  unsigned short* x_hi   = (unsigned short*)(ws + 33554432);
  unsigned short* x_lo   = x_hi + (size_t)M_ * DIM_;
  unsigned short* wqkv_hi = (unsigned short*)(ws + 67108864);
  unsigned short* wqkv_lo = wqkv_hi + (size_t)(3*DIM_) * DIM_;
  unsigned short* attn_hi = (unsigned short*)(ws + 134217728);
  unsigned short* attn_lo = attn_hi + (size_t)M_ * DIM_;
  unsigned short* vth_g  = (unsigned short*)(ws + 201326592);
  unsigned short* vtl_g  = (unsigned short*)(ws + 218103808);

  unsigned short* projq = x_hi;                         // x splits dead after gemm_v
  unsigned short* projk = projq + 16384;
  unsigned short* wout_hi = projk + 16384;
  unsigned short* wout_lo = wout_hi + (size_t)DIM_ * DIM_;

  // 1) splits
  split_kernel<<<dim3(M_*DIM_/4/256), 256, 0, stream>>>(x, x_hi, x_lo, M_*DIM_/4);
  split_kernel<<<dim3(3*DIM_*DIM_/4/256), 256, 0, stream>>>(w_qkv, wqkv_hi, wqkv_lo, 3*DIM_*DIM_/4);
  // 2) q,k = x @ w_qkv[0:1024]^T  (single bf16, bf16 out)
  mfma_gemm_nt<0,1><<<dim3(8, M_/128), 256, 0, stream>>>(
      x_hi, x_hi, wqkv_hi, wqkv_hi, qkv_bf, nullptr, DIM_, 1024, nullptr, nullptr);
  // 3) v = x @ w_qkv[1024:1536]^T (split) -> transposed hi/lo chunk layout directly
  mfma_gemm_nt<1,2><<<dim3(4, M_/128), 256, 0, stream>>>(
      x_hi, x_lo, wqkv_hi + (size_t)1024*DIM_, wqkv_lo + (size_t)1024*DIM_,
      nullptr, nullptr, DIM_, 0, vth_g, vtl_g);
  // 4) proj -> bf16 (q pre-scaled by 1/8); x splits dead now
  prep_proj<<<dim3(16), 256, 0, stream>>>(proj, projq, projk);
  // 5) fully fused per-chunk Performer
  fused_chunk<<<dim3(NCHUNK_), 256, 0, stream>>>(qkv_bf, projq, projk, vth_g, vtl_g,
                                                 attn_hi, attn_lo);
  // 6) w_out split, then out = attn @ w_out^T + b_out (split)
  split_kernel<<<dim3(DIM_*DIM_/4/256), 256, 0, stream>>>(w_out, wout_hi, wout_lo, DIM_*DIM_/4);
  mfma_gemm_nt<1,0><<<dim3(4, M_/128), 256, 0, stream>>>(
      attn_hi, attn_lo, wout_hi, wout_lo, out, b_out, DIM_, DIM_, nullptr, nullptr);
}